// Round 16
// baseline (390.676 us; speedup 1.0000x reference)
//
#include <hip/hip_runtime.h>
#include <hip/hip_bf16.h>

#define NNODES 50000
#define NPAD   50048   // NNODES rounded up to 64 (pad rows for OOB-safe frag reads)
#define NEDGES 400000
#define ETOT   (NEDGES + NNODES)
#define CIN    15
#define HID    128
#define HEADS  4
#define EPS_BN 1e-5f
#define NB_SCAN ((NNODES + 255) / 256)   // 196 blocks

typedef __attribute__((ext_vector_type(8))) short bf16x8_t;   // 8 bf16 = 4 VGPR
typedef __attribute__((ext_vector_type(4))) float f32x4_t;    // MFMA 16x16 acc

__device__ __forceinline__ float bfu(unsigned short u) {
  return __uint_as_float(((unsigned)u) << 16);
}
__device__ __forceinline__ unsigned short f2bf(float x) {
  union { __hip_bfloat16 b; unsigned short u; } c;
  c.b = __float2bfloat16(x);
  return c.u;
}
__device__ __forceinline__ float lrelu02(float x) {
  return x > 0.0f ? x : 0.2f * x;
}

// ---------------------------------------------------------------------------
// Split-bf16 MFMA GEMM, staging-free: A stored as split hi/lo bf16 planes
// (Ahg/Alg, [NPAD][KT]); each lane loads its MFMA fragments DIRECTLY from
// global (16B/lane; wave = 16 rows x 64B segments -> L2-friendly).
// No LDS A-stage, no conversion, no pre-MFMA barrier. LDS = C-stage only.
// omode: 1 = single bf16 out (CoutA), 2 = split hi/lo out (CoutA/CoutB).
// FUSEH=1: compute head projections from C-stage, write d_out (CoutA).
// ---------------------------------------------------------------------------
template <int WPT, int KT, int FUSEH>
__global__ __launch_bounds__(256) void gemm_mfma_kernel(
    const unsigned short* __restrict__ Ahg, const unsigned short* __restrict__ Alg,
    const unsigned short* __restrict__ WTh, const unsigned short* __restrict__ WTl,
    const float* __restrict__ bias,
    const float* __restrict__ bg, const float* __restrict__ bb,
    const float* __restrict__ bm, const float* __restrict__ bv,
    void* __restrict__ CoutA, void* __restrict__ CoutB, int act, int omode,
    const float* __restrict__ w_m2, const float* __restrict__ b_m2,
    const float* __restrict__ w_i2, const float* __restrict__ b_i2,
    const float* __restrict__ w_e2, const float* __restrict__ b_e2) {
  constexpr int NC = WPT * 64;
  constexpr int CST = NC + 4;          // C-stage stride (words)
  __shared__ __align__(16) float Cs[64 * CST];

  const int tid = threadIdx.x;
  const int bm_ = blockIdx.x * 64;
  const int wv = tid >> 6, l = tid & 63;
  const int lcol = l & 15;
  const int kg = (l >> 4) << 3;
  const int colbase = wv * (WPT * 16);

  f32x4_t acc[4][WPT];
#pragma unroll
  for (int rt = 0; rt < 4; ++rt)
#pragma unroll
    for (int jj = 0; jj < WPT; ++jj) acc[rt][jj] = (f32x4_t){0.f, 0.f, 0.f, 0.f};

#pragma unroll
  for (int kc = 0; kc < KT / 32; ++kc) {
    // this kc's B fragments (bounded register pressure)
    bf16x8_t cbh[WPT], cbl[WPT];
#pragma unroll
    for (int jj = 0; jj < WPT; ++jj) {
      size_t boff = (size_t)(colbase + jj * 16 + lcol) * KT + kc * 32 + kg;
      cbh[jj] = *(const bf16x8_t*)(WTh + boff);
      cbl[jj] = *(const bf16x8_t*)(WTl + boff);
    }
#pragma unroll
    for (int rt = 0; rt < 4; ++rt) {
      size_t aoff = (size_t)(bm_ + rt * 16 + (l & 15)) * KT + kc * 32 + kg;
      bf16x8_t ah = *(const bf16x8_t*)(Ahg + aoff);
      bf16x8_t al = *(const bf16x8_t*)(Alg + aoff);
#pragma unroll
      for (int jj = 0; jj < WPT; ++jj) {
        acc[rt][jj] = __builtin_amdgcn_mfma_f32_16x16x32_bf16(ah, cbh[jj], acc[rt][jj], 0, 0, 0);
        acc[rt][jj] = __builtin_amdgcn_mfma_f32_16x16x32_bf16(ah, cbl[jj], acc[rt][jj], 0, 0, 0);
        acc[rt][jj] = __builtin_amdgcn_mfma_f32_16x16x32_bf16(al, cbh[jj], acc[rt][jj], 0, 0, 0);
      }
    }
  }

  // epilogue: stage epi(C) into LDS (C/D layout m89: col=lane&15,
  // row=(lane>>4)*4+reg)
#pragma unroll
  for (int rt = 0; rt < 4; ++rt) {
    int trow0 = rt * 16 + ((l >> 4) << 2);
#pragma unroll
    for (int jj = 0; jj < WPT; ++jj) {
      int col = colbase + jj * 16 + lcol;
      float bs = bias ? bias[col] : 0.0f;
#pragma unroll
      for (int r = 0; r < 4; ++r) {
        float vv = acc[rt][jj][r] + bs;
        if (bg) vv = bg[col] * (vv - bm[col]) * rsqrtf(bv[col] + EPS_BN) + bb[col];
        if (act) vv = fmaxf(vv, 0.0f);
        Cs[(trow0 + r) * CST + col] = vv;
      }
    }
  }
  __syncthreads();

  if (FUSEH) {
    // heads: 4 threads per row; quad shfl_xor reduce; q==0 writes 5 outputs.
    int r = tid >> 2, q = tid & 3;
    int grow = bm_ + r;
    const float* row = &Cs[r * CST];
    float p0 = 0.f, p1 = 0.f, p2 = 0.f, p3 = 0.f, p4 = 0.f;
#pragma unroll
    for (int e = 0; e < 16; ++e) {
      int c = q * 16 + e;
      float hm = row[c], hi = row[64 + c], he = row[128 + c];
      p0 += hm * w_m2[c * 2 + 0];
      p1 += hm * w_m2[c * 2 + 1];
      p2 += hi * w_i2[c * 2 + 0];
      p3 += hi * w_i2[c * 2 + 1];
      p4 += he * w_e2[c];
    }
#pragma unroll
    for (int off = 1; off < 4; off <<= 1) {
      p0 += __shfl_xor(p0, off);
      p1 += __shfl_xor(p1, off);
      p2 += __shfl_xor(p2, off);
      p3 += __shfl_xor(p3, off);
      p4 += __shfl_xor(p4, off);
    }
    if (q == 0 && grow < NNODES) {
      float* out = (float*)CoutA;
      out[grow * 2 + 0] = p0 + b_m2[0];
      out[grow * 2 + 1] = p1 + b_m2[1];
      out[2 * NNODES + grow * 2 + 0] = p2 + b_i2[0];
      out[2 * NNODES + grow * 2 + 1] = p3 + b_i2[1];
      out[4 * NNODES + grow] = p4 + b_e2[0];
    }
  } else {
    constexpr int NJ = (64 * NC) / 1024;   // float4s per thread
#pragma unroll
    for (int j = 0; j < NJ; ++j) {
      int f = tid * 4 + j * 1024;
      int r = f / NC, c = f - r * NC;
      int grow = bm_ + r;
      if (grow >= NNODES) continue;
      float4 v = *(const float4*)&Cs[r * CST + c];
      ushort4 hi4;
      hi4.x = f2bf(v.x); hi4.y = f2bf(v.y); hi4.z = f2bf(v.z); hi4.w = f2bf(v.w);
      *(ushort4*)&((unsigned short*)CoutA)[(size_t)grow * NC + c] = hi4;
      if (omode == 2) {
        ushort4 lo4;
        lo4.x = f2bf(v.x - bfu(hi4.x));
        lo4.y = f2bf(v.y - bfu(hi4.y));
        lo4.z = f2bf(v.z - bfu(hi4.z));
        lo4.w = f2bf(v.w - bfu(hi4.w));
        *(ushort4*)&((unsigned short*)CoutB)[(size_t)grow * NC + c] = lo4;
      }
    }
  }
}

// ---------------------------------------------------------------------------
// GAT precompute: wv_s[k,h] = sum_c w_gat[k, h*128+c]*att_s[h,c] (and _d)
// ---------------------------------------------------------------------------
__global__ void prep_att_kernel(const float* __restrict__ w,
                                const float* __restrict__ att_s,
                                const float* __restrict__ att_d,
                                float* __restrict__ wv_s,
                                float* __restrict__ wv_d) {
  int t = threadIdx.x;
  if (t >= 60) return;
  int k = t / 4, h = t & 3;
  float s = 0.f, d = 0.f;
  for (int c = 0; c < 128; ++c) {
    float wk = w[(size_t)k * 512 + h * 128 + c];
    s += wk * att_s[h * 128 + c];
    d += wk * att_d[h * 128 + c];
  }
  wv_s[k * 4 + h] = s;
  wv_d[k * 4 + h] = d;
}

// Pack post-GAT weight: Wp[c][j] = 0.25*w_gat[k, h*128+c], j=h*15+k (64-pad)
__global__ void pack_wtp_kernel(const float* __restrict__ w,
                                unsigned short* __restrict__ WTh,
                                unsigned short* __restrict__ WTl) {
  int i = blockIdx.x * blockDim.x + threadIdx.x;
  if (i >= 128 * 64) return;
  int c = i >> 6, j = i & 63;
  float xv = 0.f;
  if (j < 60) {
    int h = j / 15, k = j - h * 15;
    xv = 0.25f * w[(size_t)k * 512 + h * 128 + c];
  }
  unsigned short hh = f2bf(xv);
  WTh[i] = hh;
  WTl[i] = f2bf(xv - bfu(hh));
}

// ---------------------------------------------------------------------------
// Per-node attention logits: a_s[n,h] = sum_k x[n,k]*wv_s[k,h]
// ---------------------------------------------------------------------------
__global__ __launch_bounds__(256) void a_sd_kernel(
    const float* __restrict__ x, const float* __restrict__ wv_s,
    const float* __restrict__ wv_d, float* __restrict__ a_s,
    float* __restrict__ a_d) {
  __shared__ float xs[256 * 15];
  __shared__ float wvs[60], wvd[60];
  int t = threadIdx.x;
  int base = blockIdx.x * 256;
  if (t < 60) { wvs[t] = wv_s[t]; wvd[t] = wv_d[t]; }
  for (int i = t; i < 256 * 15; i += 256) {
    int gi = base * 15 + i;
    xs[i] = (gi < NNODES * 15) ? x[gi] : 0.0f;
  }
  __syncthreads();
  int n = base + t;
  if (n >= NNODES) return;
  float a0 = 0, a1 = 0, a2 = 0, a3 = 0, d0 = 0, d1 = 0, d2 = 0, d3 = 0;
#pragma unroll
  for (int k = 0; k < 15; ++k) {
    float xv = xs[t * 15 + k];
    a0 += xv * wvs[k * 4 + 0]; a1 += xv * wvs[k * 4 + 1];
    a2 += xv * wvs[k * 4 + 2]; a3 += xv * wvs[k * 4 + 3];
    d0 += xv * wvd[k * 4 + 0]; d1 += xv * wvd[k * 4 + 1];
    d2 += xv * wvd[k * 4 + 2]; d3 += xv * wvd[k * 4 + 3];
  }
  float4 A; A.x = a0; A.y = a1; A.z = a2; A.w = a3;
  float4 D; D.x = d0; D.y = d1; D.z = d2; D.w = d3;
  *(float4*)&a_s[n * 4] = A;
  *(float4*)&a_d[n * 4] = D;
}

// ---------------------------------------------------------------------------
// Fused GAT gather over x: wave per node; lane<60 -> (h=lane/15, k=lane%15).
// SINGLE pass (no max needed: |logits| <~ 12), unroll-4 for MLP.
// Writes g split hi/lo bf16.
// ---------------------------------------------------------------------------
__global__ __launch_bounds__(256) void gat_fused_kernel(
    const float* __restrict__ x, const float* __restrict__ a_s,
    const float* __restrict__ a_d, const int* __restrict__ rowptr,
    const int* __restrict__ csr_src, unsigned short* __restrict__ gh,
    unsigned short* __restrict__ gl) {
  int wid = threadIdx.x >> 6, lane = threadIdx.x & 63;
  int n = blockIdx.x * 4 + wid;
  if (n >= NNODES) return;
  int e0 = rowptr[n], e1 = rowptr[n + 1];
  bool on = lane < 60;
  int h = on ? (lane / 15) : 0;
  int k = on ? (lane - h * 15) : 0;
  float adn = a_d[n * 4 + h];

  float ssum = 0.f, acc = 0.f;
  int e = e0;
  for (; e + 4 <= e1; e += 4) {
    int s0 = csr_src[e + 0], s1 = csr_src[e + 1];
    int s2 = csr_src[e + 2], s3 = csr_src[e + 3];
    float as0 = a_s[s0 * 4 + h], as1 = a_s[s1 * 4 + h];
    float as2 = a_s[s2 * 4 + h], as3 = a_s[s3 * 4 + h];
    float x0 = x[(size_t)s0 * CIN + k], x1 = x[(size_t)s1 * CIN + k];
    float x2 = x[(size_t)s2 * CIN + k], x3 = x[(size_t)s3 * CIN + k];
    float ex0 = __expf(lrelu02(as0 + adn));
    float ex1 = __expf(lrelu02(as1 + adn));
    float ex2 = __expf(lrelu02(as2 + adn));
    float ex3 = __expf(lrelu02(as3 + adn));
    ssum += (ex0 + ex1) + (ex2 + ex3);
    acc += ex0 * x0 + ex1 * x1 + ex2 * x2 + ex3 * x3;
  }
  for (; e < e1; ++e) {
    int s = csr_src[e];
    float ex = __expf(lrelu02(a_s[s * 4 + h] + adn));
    ssum += ex;
    acc += ex * x[(size_t)s * CIN + k];
  }
  float v = on ? acc / (ssum + 1e-16f) : 0.0f;
  unsigned short hv = f2bf(v);
  gh[(size_t)n * 64 + lane] = hv;
  gl[(size_t)n * 64 + lane] = f2bf(v - bfu(hv));
}

// ---------------------------------------------------------------------------
// Fused pack of the four 128x128 weights -> [N][K] bf16 hi/lo (transposed)
// ---------------------------------------------------------------------------
__global__ void pack_wt4_kernel(
    const float* __restrict__ w2, const float* __restrict__ w3,
    const float* __restrict__ w4, const float* __restrict__ ws,
    unsigned short* __restrict__ Hbase, unsigned short* __restrict__ Lbase) {
  int i = blockIdx.x * blockDim.x + threadIdx.x;
  if (i >= 128 * 128) return;
  const float* W = (blockIdx.y == 0) ? w2 : (blockIdx.y == 1) ? w3
                 : (blockIdx.y == 2) ? w4 : ws;
  unsigned short* Wh = Hbase + (size_t)blockIdx.y * 128 * 128;
  unsigned short* Wl = Lbase + (size_t)blockIdx.y * 128 * 128;
  int k = i >> 7, n = i & 127;
  float x = W[i];
  unsigned short h = f2bf(x);
  Wh[n * 128 + k] = h;
  Wl[n * 128 + k] = f2bf(x - bfu(h));
}

// Pack the three 128x64 head weights into WT192 [192][128] hi/lo + b192
__global__ void pack_wt192_kernel(
    const float* __restrict__ w_m1, const float* __restrict__ w_i1,
    const float* __restrict__ w_e1, const float* __restrict__ b_m1,
    const float* __restrict__ b_i1, const float* __restrict__ b_e1,
    unsigned short* __restrict__ WTh, unsigned short* __restrict__ WTl,
    float* __restrict__ b192) {
  int i = blockIdx.x * blockDim.x + threadIdx.x;
  if (i < 192 * 128) {
    int n = i >> 7, k = i & 127;
    float x = (n < 64) ? w_m1[k * 64 + n]
            : (n < 128) ? w_i1[k * 64 + (n - 64)]
                        : w_e1[k * 64 + (n - 128)];
    unsigned short h = f2bf(x);
    WTh[(size_t)n * 128 + k] = h;
    WTl[(size_t)n * 128 + k] = f2bf(x - bfu(h));
  }
  if (i < 192) {
    b192[i] = (i < 64) ? b_m1[i] : (i < 128) ? b_i1[i - 64] : b_e1[i - 128];
  }
}

// ---------------------------------------------------------------------------
// CSR build: count+deg -> hierarchical scan -> dinv -> scatter(normalized)
// ---------------------------------------------------------------------------
__global__ void count_deg_kernel(const int* __restrict__ ei,
                                 const float* __restrict__ ea,
                                 int* __restrict__ cnt,
                                 float* __restrict__ deg) {
  int i = blockIdx.x * blockDim.x + threadIdx.x;
  if (i >= ETOT) return;
  int d; float w;
  if (i < NEDGES) { d = ei[NEDGES + i]; w = ea[i]; }
  else            { d = i - NEDGES; w = 1.0f; }
  atomicAdd(&cnt[d], 1);
  atomicAdd(&deg[d], w);
}

__global__ __launch_bounds__(256) void csr_reduce_kernel(
    const int* __restrict__ cnt, int* __restrict__ bsum) {
  __shared__ int red[256];
  int t = threadIdx.x;
  int i = blockIdx.x * 256 + t;
  red[t] = (i < NNODES) ? cnt[i] : 0;
  __syncthreads();
  for (int off = 128; off > 0; off >>= 1) {
    if (t < off) red[t] += red[t + off];
    __syncthreads();
  }
  if (t == 0) bsum[blockIdx.x] = red[0];
}

__global__ __launch_bounds__(256) void csr_scanb_kernel(
    const int* __restrict__ bsum, int* __restrict__ boff) {
  __shared__ int s[256];
  int t = threadIdx.x;
  s[t] = (t < NB_SCAN) ? bsum[t] : 0;
  __syncthreads();
  for (int off = 1; off < 256; off <<= 1) {
    int u = (t >= off) ? s[t - off] : 0;
    __syncthreads();
    s[t] += u;
    __syncthreads();
  }
  if (t < NB_SCAN) boff[t] = (t == 0) ? 0 : s[t - 1];
}

__global__ __launch_bounds__(256) void csr_scan_kernel(
    int* __restrict__ cnt, const int* __restrict__ boff,
    int* __restrict__ rowptr) {
  __shared__ int s[256];
  int t = threadIdx.x;
  int i = blockIdx.x * 256 + t;
  int v = (i < NNODES) ? cnt[i] : 0;
  s[t] = v;
  __syncthreads();
  for (int off = 1; off < 256; off <<= 1) {
    int u = (t >= off) ? s[t - off] : 0;
    __syncthreads();
    s[t] += u;
    __syncthreads();
  }
  if (i < NNODES) {
    rowptr[i] = boff[blockIdx.x] + s[t] - v;  // exclusive
    cnt[i] = 0;                               // reset -> scatter cursor
  }
  if (i == 0) rowptr[NNODES] = ETOT;
}

__global__ void dinv_kernel(const float* __restrict__ deg,
                            float* __restrict__ dinv) {
  int n = blockIdx.x * blockDim.x + threadIdx.x;
  if (n >= NNODES) return;
  float s = deg[n];
  dinv[n] = (s > 0.0f) ? rsqrtf(fmaxf(s, 1e-12f)) : 0.0f;
}

// scatter with pre-normalized GCN weight dinv[s]*w*dinv[d]
__global__ void scatter_kernel(const int* __restrict__ ei,
                               const float* __restrict__ ea,
                               const float* __restrict__ dinv,
                               const int* __restrict__ rowptr,
                               int* __restrict__ cursor,
                               int* __restrict__ csr_src,
                               float* __restrict__ csr_ew) {
  int i = blockIdx.x * blockDim.x + threadIdx.x;
  if (i >= ETOT) return;
  int s, d; float w;
  if (i < NEDGES) { s = ei[i]; d = ei[NEDGES + i]; w = ea[i]; }
  else            { s = d = i - NEDGES; w = 1.0f; }
  int pos = rowptr[d] + atomicAdd(&cursor[d], 1);
  csr_src[pos] = s;
  csr_ew[pos] = dinv[s] * w * dinv[d];
}

// ---------------------------------------------------------------------------
// GCN gather: wave per node; h bf16; csr_w prenormalized; unroll-4 for MLP;
// BN+ReLU fused; writes split hi/lo bf16 output planes.
// ---------------------------------------------------------------------------
__global__ __launch_bounds__(256) void gcn_gather_kernel(
    const __hip_bfloat16* __restrict__ h, const int* __restrict__ rowptr,
    const int* __restrict__ csr_src, const float* __restrict__ csr_w,
    const float* __restrict__ bias,
    const float* __restrict__ bg, const float* __restrict__ bb,
    const float* __restrict__ bm, const float* __restrict__ bv,
    unsigned short* __restrict__ outh, unsigned short* __restrict__ outl) {
  int wid = threadIdx.x >> 6, lane = threadIdx.x & 63;
  int n = blockIdx.x * 4 + wid;
  if (n >= NNODES) return;
  int e0 = rowptr[n], e1 = rowptr[n + 1];
  int c = 2 * lane;
  float ax = 0.f, ay = 0.f;
  int e = e0;
  for (; e + 4 <= e1; e += 4) {
    int s0 = csr_src[e + 0], s1 = csr_src[e + 1];
    int s2 = csr_src[e + 2], s3 = csr_src[e + 3];
    float w0 = csr_w[e + 0], w1 = csr_w[e + 1];
    float w2 = csr_w[e + 2], w3 = csr_w[e + 3];
    ushort2 u0 = *(const ushort2*)(h + (size_t)s0 * HID + c);
    ushort2 u1 = *(const ushort2*)(h + (size_t)s1 * HID + c);
    ushort2 u2 = *(const ushort2*)(h + (size_t)s2 * HID + c);
    ushort2 u3 = *(const ushort2*)(h + (size_t)s3 * HID + c);
    ax += w0 * bfu(u0.x) + w1 * bfu(u1.x) + w2 * bfu(u2.x) + w3 * bfu(u3.x);
    ay += w0 * bfu(u0.y) + w1 * bfu(u1.y) + w2 * bfu(u2.y) + w3 * bfu(u3.y);
  }
  for (; e < e1; ++e) {
    int s = csr_src[e];
    float w = csr_w[e];
    ushort2 u = *(const ushort2*)(h + (size_t)s * HID + c);
    ax += w * bfu(u.x);
    ay += w * bfu(u.y);
  }
  float ox = ax + bias[c];
  float oy = ay + bias[c + 1];
  ox = bg[c] * (ox - bm[c]) * rsqrtf(bv[c] + EPS_BN) + bb[c];
  oy = bg[c + 1] * (oy - bm[c + 1]) * rsqrtf(bv[c + 1] + EPS_BN) + bb[c + 1];
  ox = fmaxf(ox, 0.0f); oy = fmaxf(oy, 0.0f);
  ushort2 hi2, lo2;
  hi2.x = f2bf(ox); hi2.y = f2bf(oy);
  lo2.x = f2bf(ox - bfu(hi2.x));
  lo2.y = f2bf(oy - bfu(hi2.y));
  *(ushort2*)&outh[(size_t)n * HID + c] = hi2;
  *(ushort2*)&outl[(size_t)n * HID + c] = lo2;
}

// ---------------------------------------------------------------------------
extern "C" void kernel_launch(void* const* d_in, const int* in_sizes, int n_in,
                              void* d_out, int out_size, void* d_ws, size_t ws_size,
                              hipStream_t stream) {
  const float* x       = (const float*)d_in[0];
  const int*   ei      = (const int*)d_in[1];
  const float* ea      = (const float*)d_in[2];
  const float* w_gat   = (const float*)d_in[3];
  const float* att_src = (const float*)d_in[4];
  const float* att_dst = (const float*)d_in[5];
  const float* b_gat   = (const float*)d_in[6];
  const float* w2 = (const float*)d_in[7];  const float* b2 = (const float*)d_in[8];
  const float* w3 = (const float*)d_in[9];  const float* b3 = (const float*)d_in[10];
  const float* w4 = (const float*)d_in[11]; const float* b4 = (const float*)d_in[12];
  const float* bn_g = (const float*)d_in[13];
  const float* bn_b = (const float*)d_in[14];
  const float* bn_m = (const float*)d_in[15];
  const float* bn_v = (const float*)d_in[16];
  const float* w_shared = (const float*)d_in[17]; const float* b_shared = (const float*)d_in[18];
  const float* w_m1 = (const float*)d_in[19]; const float* b_m1 = (const float*)d_in[20];
  const float* w_m2 = (const float*)d_in[21]; const float* b_m2 = (const float*)d_in[22];
  const float* w_i1 = (const float*)d_in[23]; const float* b_i1 = (const float*)d_in[24];
  const float* w_i2 = (const float*)d_in[25]; const float* b_i2 = (const float*)d_in[26];
  const float* w_e1 = (const float*)d_in[27]; const float* b_e1 = (const float*)d_in[28];
  const float* w_e2 = (const float*)d_in[29]; const float* b_e2 = (const float*)d_in[30];
  float* out = (float*)d_out;

  // ---- workspace layout ----
  size_t off = 0;
  auto alloc = [&](size_t bytes) -> char* {
    char* p = (char*)d_ws + off;
    off += (bytes + 255) & ~(size_t)255;
    return p;
  };
  // split activation planes (padded to NPAD rows for OOB-safe frag reads)
  unsigned short* p0h = (unsigned short*)alloc((size_t)NPAD * HID * 2);
  unsigned short* p0l = (unsigned short*)alloc((size_t)NPAD * HID * 2);
  unsigned short* p1h = (unsigned short*)alloc((size_t)NPAD * HID * 2);
  unsigned short* p1l = (unsigned short*)alloc((size_t)NPAD * HID * 2);
  unsigned short* gh  = (unsigned short*)alloc((size_t)NPAD * 64 * 2);
  unsigned short* gl  = (unsigned short*)alloc((size_t)NPAD * 64 * 2);
  __hip_bfloat16* hb  = (__hip_bfloat16*)alloc((size_t)NPAD * HID * 2);
  float* a_s     = (float*)alloc((size_t)NNODES * 4 * 4);
  float* a_d     = (float*)alloc((size_t)NNODES * 4 * 4);
  float* deg     = (float*)alloc((size_t)NNODES * 4);
  float* dinv    = (float*)alloc((size_t)NNODES * 4);
  float* csr_ew  = (float*)alloc((size_t)ETOT * 4);
  int*   rowptr  = (int*)alloc((size_t)(NNODES + 1) * 4);
  int*   cnt     = (int*)alloc((size_t)NNODES * 4);
  int*   csr_src = (int*)alloc((size_t)ETOT * 4);
  int*   bsum    = (int*)alloc((size_t)NB_SCAN * 4);
  int*   boff    = (int*)alloc((size_t)NB_SCAN * 4);
  // split-bf16 transposed weights
  unsigned short* wtH = (unsigned short*)alloc(4 * 128 * 128 * 2);
  unsigned short* wtL = (unsigned short*)alloc(4 * 128 * 128 * 2);
  unsigned short* wt192h = (unsigned short*)alloc(192 * 128 * 2);
  unsigned short* wt192l = (unsigned short*)alloc(192 * 128 * 2);
  unsigned short* wtph = (unsigned short*)alloc(128 * 64 * 2);
  unsigned short* wtpl = (unsigned short*)alloc(128 * 64 * 2);
  float* b192 = (float*)alloc(192 * 4);
  float* wv_s = (float*)alloc(60 * 4);
  float* wv_d = (float*)alloc(60 * 4);

  unsigned short* wt2h = wtH + 0 * 16384; unsigned short* wt2l = wtL + 0 * 16384;
  unsigned short* wt3h = wtH + 1 * 16384; unsigned short* wt3l = wtL + 1 * 16384;
  unsigned short* wt4h = wtH + 2 * 16384; unsigned short* wt4l = wtL + 2 * 16384;
  unsigned short* wsh  = wtH + 3 * 16384; unsigned short* wsl  = wtL + 3 * 16384;

  dim3 blk256(256);
  dim3 wgrid((NNODES + 3) / 4);
  dim3 mgrid((NNODES + 63) / 64);

  // 1) CSR build: count+deg -> scan (zeroes cnt) -> dinv -> scatter(norm'd)
  hipMemsetAsync(cnt, 0, NNODES * 4, stream);
  hipMemsetAsync(deg, 0, NNODES * 4, stream);
  count_deg_kernel<<<(ETOT + 255) / 256, blk256, 0, stream>>>(ei, ea, cnt, deg);
  csr_reduce_kernel<<<NB_SCAN, blk256, 0, stream>>>(cnt, bsum);
  csr_scanb_kernel<<<1, blk256, 0, stream>>>(bsum, boff);
  csr_scan_kernel<<<NB_SCAN, blk256, 0, stream>>>(cnt, boff, rowptr);
  dinv_kernel<<<(NNODES + 255) / 256, blk256, 0, stream>>>(deg, dinv);
  scatter_kernel<<<(ETOT + 255) / 256, blk256, 0, stream>>>(
      ei, ea, dinv, rowptr, cnt, csr_src, csr_ew);

  // 2) precompute + packs (independent)
  prep_att_kernel<<<1, 64, 0, stream>>>(w_gat, att_src, att_dst, wv_s, wv_d);
  pack_wtp_kernel<<<(128 * 64 + 255) / 256, blk256, 0, stream>>>(w_gat, wtph, wtpl);
  pack_wt4_kernel<<<dim3((128 * 128 + 255) / 256, 4), blk256, 0, stream>>>(
      w2, w3, w4, w_shared, wtH, wtL);
  pack_wt192_kernel<<<(192 * 128 + 255) / 256, blk256, 0, stream>>>(
      w_m1, w_i1, w_e1, b_m1, b_i1, b_e1, wt192h, wt192l, b192);

  // 3) per-node attention logits
  a_sd_kernel<<<NB_SCAN, blk256, 0, stream>>>(x, wv_s, wv_d, a_s, a_d);

  // 4) fused GAT gather over x -> g split [NPAD,64]
  gat_fused_kernel<<<wgrid, blk256, 0, stream>>>(
      x, a_s, a_d, rowptr, csr_src, gh, gl);

  // 5) GAT post-GEMM: p0(split) = relu(BN0(g @ Wp + b_gat))
  gemm_mfma_kernel<2, 64, 0><<<mgrid, blk256, 0, stream>>>(
      gh, gl, wtph, wtpl, b_gat, bn_g + 0, bn_b + 0, bn_m + 0, bn_v + 0,
      p0h, p0l, 1, 2, nullptr, nullptr, nullptr, nullptr, nullptr, nullptr);

  // 6) GCN layer 2: hb(bf16) = p0 @ w2 ; gather -> p1(split)
  gemm_mfma_kernel<2, 128, 0><<<mgrid, blk256, 0, stream>>>(
      p0h, p0l, wt2h, wt2l, nullptr, nullptr, nullptr, nullptr, nullptr,
      hb, nullptr, 0, 1, nullptr, nullptr, nullptr, nullptr, nullptr, nullptr);
  gcn_gather_kernel<<<wgrid, blk256, 0, stream>>>(
      hb, rowptr, csr_src, csr_ew, b2,
      bn_g + 128, bn_b + 128, bn_m + 128, bn_v + 128, p1h, p1l);

  // 7) GCN layer 3
  gemm_mfma_kernel<2, 128, 0><<<mgrid, blk256, 0, stream>>>(
      p1h, p1l, wt3h, wt3l, nullptr, nullptr, nullptr, nullptr, nullptr,
      hb, nullptr, 0, 1, nullptr, nullptr, nullptr, nullptr, nullptr, nullptr);
  gcn_gather_kernel<<<wgrid, blk256, 0, stream>>>(
      hb, rowptr, csr_src, csr_ew, b3,
      bn_g + 256, bn_b + 256, bn_m + 256, bn_v + 256, p0h, p0l);

  // 8) GCN layer 4
  gemm_mfma_kernel<2, 128, 0><<<mgrid, blk256, 0, stream>>>(
      p0h, p0l, wt4h, wt4l, nullptr, nullptr, nullptr, nullptr, nullptr,
      hb, nullptr, 0, 1, nullptr, nullptr, nullptr, nullptr, nullptr, nullptr);
  gcn_gather_kernel<<<wgrid, blk256, 0, stream>>>(
      hb, rowptr, csr_src, csr_ew, b4,
      bn_g + 384, bn_b + 384, bn_m + 384, bn_v + 384, p1h, p1l);

  // 9) hs(split) = relu(p1 @ w_shared + b_shared) -> p0 planes
  gemm_mfma_kernel<2, 128, 0><<<mgrid, blk256, 0, stream>>>(
      p1h, p1l, wsh, wsl, b_shared, nullptr, nullptr, nullptr, nullptr,
      p0h, p0l, 1, 2, nullptr, nullptr, nullptr, nullptr, nullptr, nullptr);

  // 10) h192 GEMM + fused heads -> d_out (no h192 materialization)
  gemm_mfma_kernel<3, 128, 1><<<mgrid, blk256, 0, stream>>>(
      p0h, p0l, wt192h, wt192l, b192, nullptr, nullptr, nullptr, nullptr,
      out, nullptr, 1, 0, w_m2, b_m2, w_i2, b_i2, w_e2, b_e2);
}

// Round 17
// 328.317 us; speedup vs baseline: 1.1899x; 1.1899x over previous
//
#include <hip/hip_runtime.h>
#include <hip/hip_bf16.h>

#define NNODES 50000
#define NEDGES 400000
#define ETOT   (NEDGES + NNODES)
#define CIN    15
#define HID    128
#define HEADS  4
#define EPS_BN 1e-5f
#define NB_SCAN ((NNODES + 255) / 256)   // 196 blocks

typedef __attribute__((ext_vector_type(8))) short bf16x8_t;   // 8 bf16 = 4 VGPR
typedef __attribute__((ext_vector_type(4))) float f32x4_t;    // MFMA 16x16 acc

__device__ __forceinline__ float bfu(unsigned short u) {
  return __uint_as_float(((unsigned)u) << 16);
}
__device__ __forceinline__ unsigned short f2bf(float x) {
  union { __hip_bfloat16 b; unsigned short u; } c;
  c.b = __float2bfloat16(x);
  return c.u;
}
__device__ __forceinline__ float lrelu02(float x) {
  return x > 0.0f ? x : 0.2f * x;
}

// ---------------------------------------------------------------------------
// Split-bf16 MFMA GEMM (round-15 best config): LDS-staged A, per-kc B.
// ---------------------------------------------------------------------------
template <int WPT, int KT>
__global__ __launch_bounds__(256) void gemm_mfma_kernel(
    const float* __restrict__ A, const unsigned short* __restrict__ WTh,
    const unsigned short* __restrict__ WTl, const float* __restrict__ bias,
    const float* __restrict__ bg, const float* __restrict__ bb,
    const float* __restrict__ bm, const float* __restrict__ bv,
    void* __restrict__ Cout, int act, int obf16) {
  constexpr int NC = WPT * 64;
  constexpr int CST = NC + 4;
  constexpr int CPR = KT / 8;
  constexpr int ABYTES = 64 * KT * 2 * 2;
  constexpr int CBYTES = 64 * CST * 4;
  constexpr int SBYTES = (ABYTES > CBYTES) ? ABYTES : CBYTES;
  __shared__ __align__(16) char smem[SBYTES];
  unsigned short* Ah = (unsigned short*)smem;
  unsigned short* Al = Ah + 64 * KT;
  float* Cs = (float*)smem;

  const int tid = threadIdx.x;
  const int bm_ = blockIdx.x * 64;
  const int wv = tid >> 6, l = tid & 63;
  const int lcol = l & 15;
  const int kg = (l >> 4) << 3;
  const int colbase = wv * (WPT * 16);

  // stage A tile -> hi/lo bf16 LDS, XOR-swizzled
#pragma unroll
  for (int i = 0; i < (64 * CPR) / 256; ++i) {
    int cch = tid + 256 * i;
    int r = cch / CPR, k0 = (cch % CPR) << 3;
    int gr = bm_ + r;
    float v[8];
    if (gr < NNODES) {
      float4 v0 = *(const float4*)&A[(size_t)gr * KT + k0];
      float4 v1 = *(const float4*)&A[(size_t)gr * KT + k0 + 4];
      v[0] = v0.x; v[1] = v0.y; v[2] = v0.z; v[3] = v0.w;
      v[4] = v1.x; v[5] = v1.y; v[6] = v1.z; v[7] = v1.w;
    } else {
#pragma unroll
      for (int j = 0; j < 8; ++j) v[j] = 0.0f;
    }
    bf16x8_t hv, lv;
#pragma unroll
    for (int j = 0; j < 8; ++j) {
      unsigned short h = f2bf(v[j]);
      hv[j] = (short)h;
      lv[j] = (short)f2bf(v[j] - bfu(h));
    }
    int byte = (k0 << 1) ^ ((r & 7) << 4);
    *(bf16x8_t*)((char*)(Ah + r * KT) + byte) = hv;
    *(bf16x8_t*)((char*)(Al + r * KT) + byte) = lv;
  }
  __syncthreads();

  f32x4_t acc[4][WPT];
#pragma unroll
  for (int rt = 0; rt < 4; ++rt)
#pragma unroll
    for (int jj = 0; jj < WPT; ++jj) acc[rt][jj] = (f32x4_t){0.f, 0.f, 0.f, 0.f};

#pragma unroll
  for (int kc = 0; kc < KT / 32; ++kc) {
    bf16x8_t cbh[WPT], cbl[WPT];
#pragma unroll
    for (int jj = 0; jj < WPT; ++jj) {
      size_t boff = (size_t)(colbase + jj * 16 + lcol) * KT + kc * 32 + kg;
      cbh[jj] = *(const bf16x8_t*)(WTh + boff);
      cbl[jj] = *(const bf16x8_t*)(WTl + boff);
    }
    int k = kc * 32 + kg;
#pragma unroll
    for (int rt = 0; rt < 4; ++rt) {
      int lrow = rt * 16 + (l & 15);
      int byte = (k << 1) ^ ((lrow & 7) << 4);
      bf16x8_t ah = *(const bf16x8_t*)((const char*)(Ah + lrow * KT) + byte);
      bf16x8_t al = *(const bf16x8_t*)((const char*)(Al + lrow * KT) + byte);
#pragma unroll
      for (int jj = 0; jj < WPT; ++jj) {
        acc[rt][jj] = __builtin_amdgcn_mfma_f32_16x16x32_bf16(ah, cbh[jj], acc[rt][jj], 0, 0, 0);
        acc[rt][jj] = __builtin_amdgcn_mfma_f32_16x16x32_bf16(ah, cbl[jj], acc[rt][jj], 0, 0, 0);
        acc[rt][jj] = __builtin_amdgcn_mfma_f32_16x16x32_bf16(al, cbh[jj], acc[rt][jj], 0, 0, 0);
      }
    }
  }

  __syncthreads();
#pragma unroll
  for (int rt = 0; rt < 4; ++rt) {
    int trow0 = rt * 16 + ((l >> 4) << 2);
#pragma unroll
    for (int jj = 0; jj < WPT; ++jj) {
      int col = colbase + jj * 16 + lcol;
      float bs = bias ? bias[col] : 0.0f;
#pragma unroll
      for (int r = 0; r < 4; ++r) {
        float vv = acc[rt][jj][r] + bs;
        if (bg) vv = bg[col] * (vv - bm[col]) * rsqrtf(bv[col] + EPS_BN) + bb[col];
        if (act) vv = fmaxf(vv, 0.0f);
        Cs[(trow0 + r) * CST + col] = vv;
      }
    }
  }
  __syncthreads();

  constexpr int NJ = (64 * NC) / 1024;
#pragma unroll
  for (int j = 0; j < NJ; ++j) {
    int f = tid * 4 + j * 1024;
    int r = f / NC, c = f - r * NC;
    int grow = bm_ + r;
    if (grow >= NNODES) continue;
    float4 v = *(const float4*)&Cs[r * CST + c];
    if (obf16) {
      ushort4 us;
      us.x = f2bf(v.x); us.y = f2bf(v.y); us.z = f2bf(v.z); us.w = f2bf(v.w);
      *(ushort4*)&((unsigned short*)Cout)[(size_t)grow * NC + c] = us;
    } else {
      *(float4*)&((float*)Cout)[(size_t)grow * NC + c] = v;
    }
  }
}

// ---------------------------------------------------------------------------
// Fused shared-layer + 192-GEMM + heads:
// per 64-row block: hs = relu(p1_tile @ Ws + b_shared) -> LDS (split bf16,
// swizzled); h192 = relu(hs @ W192 + b192) -> C-stage; head projections -> out
// ---------------------------------------------------------------------------
__global__ __launch_bounds__(256) void shared_heads_kernel(
    const float* __restrict__ A, const unsigned short* __restrict__ WSh,
    const unsigned short* __restrict__ WSl, const float* __restrict__ b_shared,
    const unsigned short* __restrict__ W2h, const unsigned short* __restrict__ W2l,
    const float* __restrict__ b192,
    const float* __restrict__ w_m2, const float* __restrict__ b_m2,
    const float* __restrict__ w_i2, const float* __restrict__ b_i2,
    const float* __restrict__ w_e2, const float* __restrict__ b_e2,
    float* __restrict__ out) {
  constexpr int KT = 128;
  constexpr int CST = 196;                 // 192 + 4
  constexpr int AC_BYTES = 64 * CST * 4;   // 50176 (C-stage, aliases A-stage 32KB)
  __shared__ __align__(16) char smem[AC_BYTES + 64 * KT * 2 * 2];
  unsigned short* Ah = (unsigned short*)smem;
  unsigned short* Al = Ah + 64 * KT;
  float* Cs = (float*)smem;                              // phase-C epilogue
  unsigned short* Hh = (unsigned short*)(smem + AC_BYTES);
  unsigned short* Hl = Hh + 64 * KT;

  const int tid = threadIdx.x;
  const int bm_ = blockIdx.x * 64;
  const int wv = tid >> 6, l = tid & 63;
  const int lcol = l & 15;
  const int kg = (l >> 4) << 3;

  // ---- stage p1 tile -> split bf16 LDS (swizzled) ----
#pragma unroll
  for (int i = 0; i < 4; ++i) {
    int cch = tid + 256 * i;
    int r = cch >> 4, k0 = (cch & 15) << 3;
    int gr = bm_ + r;
    float v[8];
    if (gr < NNODES) {
      float4 v0 = *(const float4*)&A[(size_t)gr * KT + k0];
      float4 v1 = *(const float4*)&A[(size_t)gr * KT + k0 + 4];
      v[0] = v0.x; v[1] = v0.y; v[2] = v0.z; v[3] = v0.w;
      v[4] = v1.x; v[5] = v1.y; v[6] = v1.z; v[7] = v1.w;
    } else {
#pragma unroll
      for (int j = 0; j < 8; ++j) v[j] = 0.0f;
    }
    bf16x8_t hv, lv;
#pragma unroll
    for (int j = 0; j < 8; ++j) {
      unsigned short h = f2bf(v[j]);
      hv[j] = (short)h;
      lv[j] = (short)f2bf(v[j] - bfu(h));
    }
    int byte = (k0 << 1) ^ ((r & 7) << 4);
    *(bf16x8_t*)((char*)(Ah + r * KT) + byte) = hv;
    *(bf16x8_t*)((char*)(Al + r * KT) + byte) = lv;
  }
  __syncthreads();

  // ---- phase B: hs = relu(p1 @ Ws + b_shared); 32 cols/wave (WPT=2) ----
  {
    const int colbase = wv * 32;
    f32x4_t acc[4][2];
#pragma unroll
    for (int rt = 0; rt < 4; ++rt)
#pragma unroll
      for (int jj = 0; jj < 2; ++jj) acc[rt][jj] = (f32x4_t){0.f, 0.f, 0.f, 0.f};
#pragma unroll
    for (int kc = 0; kc < 4; ++kc) {
      bf16x8_t cbh[2], cbl[2];
#pragma unroll
      for (int jj = 0; jj < 2; ++jj) {
        size_t boff = (size_t)(colbase + jj * 16 + lcol) * KT + kc * 32 + kg;
        cbh[jj] = *(const bf16x8_t*)(WSh + boff);
        cbl[jj] = *(const bf16x8_t*)(WSl + boff);
      }
      int k = kc * 32 + kg;
#pragma unroll
      for (int rt = 0; rt < 4; ++rt) {
        int lrow = rt * 16 + (l & 15);
        int byte = (k << 1) ^ ((lrow & 7) << 4);
        bf16x8_t ah = *(const bf16x8_t*)((const char*)(Ah + lrow * KT) + byte);
        bf16x8_t al = *(const bf16x8_t*)((const char*)(Al + lrow * KT) + byte);
#pragma unroll
        for (int jj = 0; jj < 2; ++jj) {
          acc[rt][jj] = __builtin_amdgcn_mfma_f32_16x16x32_bf16(ah, cbh[jj], acc[rt][jj], 0, 0, 0);
          acc[rt][jj] = __builtin_amdgcn_mfma_f32_16x16x32_bf16(ah, cbl[jj], acc[rt][jj], 0, 0, 0);
          acc[rt][jj] = __builtin_amdgcn_mfma_f32_16x16x32_bf16(al, cbh[jj], acc[rt][jj], 0, 0, 0);
        }
      }
    }
    // epilogue -> Hh/Hl (swizzled split bf16, same layout as A-stage)
#pragma unroll
    for (int rt = 0; rt < 4; ++rt) {
      int trow0 = rt * 16 + ((l >> 4) << 2);
#pragma unroll
      for (int jj = 0; jj < 2; ++jj) {
        int col = colbase + jj * 16 + lcol;
        float bs = b_shared[col];
#pragma unroll
        for (int r = 0; r < 4; ++r) {
          int trow = trow0 + r;
          float vv = fmaxf(acc[rt][jj][r] + bs, 0.0f);
          unsigned short hv = f2bf(vv);
          unsigned short lv = f2bf(vv - bfu(hv));
          int byte = ((trow * KT + col) << 1) ^ ((trow & 7) << 4);
          *(unsigned short*)((char*)Hh + byte) = hv;
          *(unsigned short*)((char*)Hl + byte) = lv;
        }
      }
    }
  }
  __syncthreads();

  // ---- phase C: h192 = relu(hs @ W192 + b192); 48 cols/wave (3x16) ----
  {
    const int colbase = wv * 48;
    f32x4_t acc[4][3];
#pragma unroll
    for (int rt = 0; rt < 4; ++rt)
#pragma unroll
      for (int jj = 0; jj < 3; ++jj) acc[rt][jj] = (f32x4_t){0.f, 0.f, 0.f, 0.f};
#pragma unroll
    for (int kc = 0; kc < 4; ++kc) {
      bf16x8_t cbh[3], cbl[3];
#pragma unroll
      for (int jj = 0; jj < 3; ++jj) {
        size_t boff = (size_t)(colbase + jj * 16 + lcol) * KT + kc * 32 + kg;
        cbh[jj] = *(const bf16x8_t*)(W2h + boff);
        cbl[jj] = *(const bf16x8_t*)(W2l + boff);
      }
      int k = kc * 32 + kg;
#pragma unroll
      for (int rt = 0; rt < 4; ++rt) {
        int lrow = rt * 16 + (l & 15);
        int byte = (k << 1) ^ ((lrow & 7) << 4);
        bf16x8_t ah = *(const bf16x8_t*)((const char*)(Hh + lrow * KT) + byte);
        bf16x8_t al = *(const bf16x8_t*)((const char*)(Hl + lrow * KT) + byte);
#pragma unroll
        for (int jj = 0; jj < 3; ++jj) {
          acc[rt][jj] = __builtin_amdgcn_mfma_f32_16x16x32_bf16(ah, cbh[jj], acc[rt][jj], 0, 0, 0);
          acc[rt][jj] = __builtin_amdgcn_mfma_f32_16x16x32_bf16(ah, cbl[jj], acc[rt][jj], 0, 0, 0);
          acc[rt][jj] = __builtin_amdgcn_mfma_f32_16x16x32_bf16(al, cbh[jj], acc[rt][jj], 0, 0, 0);
        }
      }
    }
    // epilogue -> C-stage (aliases the dead A-stage; phase-B reads completed
    // before the post-hs-write barrier)
#pragma unroll
    for (int rt = 0; rt < 4; ++rt) {
      int trow0 = rt * 16 + ((l >> 4) << 2);
#pragma unroll
      for (int jj = 0; jj < 3; ++jj) {
        int col = colbase + jj * 16 + lcol;
        float bs = b192[col];
#pragma unroll
        for (int r = 0; r < 4; ++r) {
          float vv = fmaxf(acc[rt][jj][r] + bs, 0.0f);
          Cs[(trow0 + r) * CST + col] = vv;
        }
      }
    }
  }
  __syncthreads();

  // ---- heads: 4 threads per row; quad shfl_xor reduce ----
  {
    int r = tid >> 2, q = tid & 3;
    int grow = bm_ + r;
    const float* row = &Cs[r * CST];
    float p0 = 0.f, p1 = 0.f, p2 = 0.f, p3 = 0.f, p4 = 0.f;
#pragma unroll
    for (int e = 0; e < 16; ++e) {
      int c = q * 16 + e;
      float hm = row[c], hi = row[64 + c], he = row[128 + c];
      p0 += hm * w_m2[c * 2 + 0];
      p1 += hm * w_m2[c * 2 + 1];
      p2 += hi * w_i2[c * 2 + 0];
      p3 += hi * w_i2[c * 2 + 1];
      p4 += he * w_e2[c];
    }
#pragma unroll
    for (int off = 1; off < 4; off <<= 1) {
      p0 += __shfl_xor(p0, off);
      p1 += __shfl_xor(p1, off);
      p2 += __shfl_xor(p2, off);
      p3 += __shfl_xor(p3, off);
      p4 += __shfl_xor(p4, off);
    }
    if (q == 0 && grow < NNODES) {
      out[grow * 2 + 0] = p0 + b_m2[0];
      out[grow * 2 + 1] = p1 + b_m2[1];
      out[2 * NNODES + grow * 2 + 0] = p2 + b_i2[0];
      out[2 * NNODES + grow * 2 + 1] = p3 + b_i2[1];
      out[4 * NNODES + grow] = p4 + b_e2[0];
    }
  }
}

// ---------------------------------------------------------------------------
// GAT precompute: wv_s[k,h] = sum_c w_gat[k, h*128+c]*att_s[h,c] (and _d)
// ---------------------------------------------------------------------------
__global__ void prep_att_kernel(const float* __restrict__ w,
                                const float* __restrict__ att_s,
                                const float* __restrict__ att_d,
                                float* __restrict__ wv_s,
                                float* __restrict__ wv_d) {
  int t = threadIdx.x;
  if (t >= 60) return;
  int k = t / 4, h = t & 3;
  float s = 0.f, d = 0.f;
  for (int c = 0; c < 128; ++c) {
    float wk = w[(size_t)k * 512 + h * 128 + c];
    s += wk * att_s[h * 128 + c];
    d += wk * att_d[h * 128 + c];
  }
  wv_s[k * 4 + h] = s;
  wv_d[k * 4 + h] = d;
}

// Pack post-GAT weight: Wp[c][j] = 0.25*w_gat[k, h*128+c], j=h*15+k (64-pad)
__global__ void pack_wtp_kernel(const float* __restrict__ w,
                                unsigned short* __restrict__ WTh,
                                unsigned short* __restrict__ WTl) {
  int i = blockIdx.x * blockDim.x + threadIdx.x;
  if (i >= 128 * 64) return;
  int c = i >> 6, j = i & 63;
  float xv = 0.f;
  if (j < 60) {
    int h = j / 15, k = j - h * 15;
    xv = 0.25f * w[(size_t)k * 512 + h * 128 + c];
  }
  unsigned short hh = f2bf(xv);
  WTh[i] = hh;
  WTl[i] = f2bf(xv - bfu(hh));
}

// ---------------------------------------------------------------------------
// Per-node attention logits: a_s[n,h] = sum_k x[n,k]*wv_s[k,h]
// ---------------------------------------------------------------------------
__global__ __launch_bounds__(256) void a_sd_kernel(
    const float* __restrict__ x, const float* __restrict__ wv_s,
    const float* __restrict__ wv_d, float* __restrict__ a_s,
    float* __restrict__ a_d) {
  __shared__ float xs[256 * 15];
  __shared__ float wvs[60], wvd[60];
  int t = threadIdx.x;
  int base = blockIdx.x * 256;
  if (t < 60) { wvs[t] = wv_s[t]; wvd[t] = wv_d[t]; }
  for (int i = t; i < 256 * 15; i += 256) {
    int gi = base * 15 + i;
    xs[i] = (gi < NNODES * 15) ? x[gi] : 0.0f;
  }
  __syncthreads();
  int n = base + t;
  if (n >= NNODES) return;
  float a0 = 0, a1 = 0, a2 = 0, a3 = 0, d0 = 0, d1 = 0, d2 = 0, d3 = 0;
#pragma unroll
  for (int k = 0; k < 15; ++k) {
    float xv = xs[t * 15 + k];
    a0 += xv * wvs[k * 4 + 0]; a1 += xv * wvs[k * 4 + 1];
    a2 += xv * wvs[k * 4 + 2]; a3 += xv * wvs[k * 4 + 3];
    d0 += xv * wvd[k * 4 + 0]; d1 += xv * wvd[k * 4 + 1];
    d2 += xv * wvd[k * 4 + 2]; d3 += xv * wvd[k * 4 + 3];
  }
  float4 A; A.x = a0; A.y = a1; A.z = a2; A.w = a3;
  float4 D; D.x = d0; D.y = d1; D.z = d2; D.w = d3;
  *(float4*)&a_s[n * 4] = A;
  *(float4*)&a_d[n * 4] = D;
}

// ---------------------------------------------------------------------------
// Fused GAT gather over x: wave per node; lane<60 -> (h=lane/15, k=lane%15).
// ---------------------------------------------------------------------------
__global__ __launch_bounds__(256) void gat_fused_kernel(
    const float* __restrict__ x, const float* __restrict__ a_s,
    const float* __restrict__ a_d, const int* __restrict__ rowptr,
    const int* __restrict__ csr_src, float* __restrict__ g) {
  int wid = threadIdx.x >> 6, lane = threadIdx.x & 63;
  int n = blockIdx.x * 4 + wid;
  if (n >= NNODES) return;
  int e0 = rowptr[n], e1 = rowptr[n + 1];
  bool on = lane < 60;
  int h = on ? (lane / 15) : 0;
  int k = on ? (lane - h * 15) : 0;
  float adn = a_d[n * 4 + h];

  float ssum = 0.f, acc = 0.f;
  int e = e0;
  for (; e + 4 <= e1; e += 4) {
    int s0 = csr_src[e + 0], s1 = csr_src[e + 1];
    int s2 = csr_src[e + 2], s3 = csr_src[e + 3];
    float as0 = a_s[s0 * 4 + h], as1 = a_s[s1 * 4 + h];
    float as2 = a_s[s2 * 4 + h], as3 = a_s[s3 * 4 + h];
    float x0 = x[(size_t)s0 * CIN + k], x1 = x[(size_t)s1 * CIN + k];
    float x2 = x[(size_t)s2 * CIN + k], x3 = x[(size_t)s3 * CIN + k];
    float ex0 = __expf(lrelu02(as0 + adn));
    float ex1 = __expf(lrelu02(as1 + adn));
    float ex2 = __expf(lrelu02(as2 + adn));
    float ex3 = __expf(lrelu02(as3 + adn));
    ssum += (ex0 + ex1) + (ex2 + ex3);
    acc += ex0 * x0 + ex1 * x1 + ex2 * x2 + ex3 * x3;
  }
  for (; e < e1; ++e) {
    int s = csr_src[e];
    float ex = __expf(lrelu02(a_s[s * 4 + h] + adn));
    ssum += ex;
    acc += ex * x[(size_t)s * CIN + k];
  }
  g[(size_t)n * 64 + lane] = on ? acc / (ssum + 1e-16f) : 0.0f;
}

// ---------------------------------------------------------------------------
// Fused pack of the four 128x128 weights -> [N][K] bf16 hi/lo (transposed)
// ---------------------------------------------------------------------------
__global__ void pack_wt4_kernel(
    const float* __restrict__ w2, const float* __restrict__ w3,
    const float* __restrict__ w4, const float* __restrict__ ws,
    unsigned short* __restrict__ Hbase, unsigned short* __restrict__ Lbase) {
  int i = blockIdx.x * blockDim.x + threadIdx.x;
  if (i >= 128 * 128) return;
  const float* W = (blockIdx.y == 0) ? w2 : (blockIdx.y == 1) ? w3
                 : (blockIdx.y == 2) ? w4 : ws;
  unsigned short* Wh = Hbase + (size_t)blockIdx.y * 128 * 128;
  unsigned short* Wl = Lbase + (size_t)blockIdx.y * 128 * 128;
  int k = i >> 7, n = i & 127;
  float x = W[i];
  unsigned short h = f2bf(x);
  Wh[n * 128 + k] = h;
  Wl[n * 128 + k] = f2bf(x - bfu(h));
}

// Pack the three 128x64 head weights into WT192 [192][128] hi/lo + b192
__global__ void pack_wt192_kernel(
    const float* __restrict__ w_m1, const float* __restrict__ w_i1,
    const float* __restrict__ w_e1, const float* __restrict__ b_m1,
    const float* __restrict__ b_i1, const float* __restrict__ b_e1,
    unsigned short* __restrict__ WTh, unsigned short* __restrict__ WTl,
    float* __restrict__ b192) {
  int i = blockIdx.x * blockDim.x + threadIdx.x;
  if (i < 192 * 128) {
    int n = i >> 7, k = i & 127;
    float x = (n < 64) ? w_m1[k * 64 + n]
            : (n < 128) ? w_i1[k * 64 + (n - 64)]
                        : w_e1[k * 64 + (n - 128)];
    unsigned short h = f2bf(x);
    WTh[(size_t)n * 128 + k] = h;
    WTl[(size_t)n * 128 + k] = f2bf(x - bfu(h));
  }
  if (i < 192) {
    b192[i] = (i < 64) ? b_m1[i] : (i < 128) ? b_i1[i - 64] : b_e1[i - 128];
  }
}

// ---------------------------------------------------------------------------
// CSR build: count+deg -> hierarchical scan -> dinv -> scatter(normalized)
// ---------------------------------------------------------------------------
__global__ void count_deg_kernel(const int* __restrict__ ei,
                                 const float* __restrict__ ea,
                                 int* __restrict__ cnt,
                                 float* __restrict__ deg) {
  int i = blockIdx.x * blockDim.x + threadIdx.x;
  if (i >= ETOT) return;
  int d; float w;
  if (i < NEDGES) { d = ei[NEDGES + i]; w = ea[i]; }
  else            { d = i - NEDGES; w = 1.0f; }
  atomicAdd(&cnt[d], 1);
  atomicAdd(&deg[d], w);
}

__global__ __launch_bounds__(256) void csr_reduce_kernel(
    const int* __restrict__ cnt, int* __restrict__ bsum) {
  __shared__ int red[256];
  int t = threadIdx.x;
  int i = blockIdx.x * 256 + t;
  red[t] = (i < NNODES) ? cnt[i] : 0;
  __syncthreads();
  for (int off = 128; off > 0; off >>= 1) {
    if (t < off) red[t] += red[t + off];
    __syncthreads();
  }
  if (t == 0) bsum[blockIdx.x] = red[0];
}

__global__ __launch_bounds__(256) void csr_scanb_kernel(
    const int* __restrict__ bsum, int* __restrict__ boff) {
  __shared__ int s[256];
  int t = threadIdx.x;
  s[t] = (t < NB_SCAN) ? bsum[t] : 0;
  __syncthreads();
  for (int off = 1; off < 256; off <<= 1) {
    int u = (t >= off) ? s[t - off] : 0;
    __syncthreads();
    s[t] += u;
    __syncthreads();
  }
  if (t < NB_SCAN) boff[t] = (t == 0) ? 0 : s[t - 1];
}

__global__ __launch_bounds__(256) void csr_scan_kernel(
    int* __restrict__ cnt, const int* __restrict__ boff,
    int* __restrict__ rowptr) {
  __shared__ int s[256];
  int t = threadIdx.x;
  int i = blockIdx.x * 256 + t;
  int v = (i < NNODES) ? cnt[i] : 0;
  s[t] = v;
  __syncthreads();
  for (int off = 1; off < 256; off <<= 1) {
    int u = (t >= off) ? s[t - off] : 0;
    __syncthreads();
    s[t] += u;
    __syncthreads();
  }
  if (i < NNODES) {
    rowptr[i] = boff[blockIdx.x] + s[t] - v;  // exclusive
    cnt[i] = 0;                               // reset -> scatter cursor
  }
  if (i == 0) rowptr[NNODES] = ETOT;
}

__global__ void dinv_kernel(const float* __restrict__ deg,
                            float* __restrict__ dinv) {
  int n = blockIdx.x * blockDim.x + threadIdx.x;
  if (n >= NNODES) return;
  float s = deg[n];
  dinv[n] = (s > 0.0f) ? rsqrtf(fmaxf(s, 1e-12f)) : 0.0f;
}

// scatter with pre-normalized GCN weight dinv[s]*w*dinv[d]
__global__ void scatter_kernel(const int* __restrict__ ei,
                               const float* __restrict__ ea,
                               const float* __restrict__ dinv,
                               const int* __restrict__ rowptr,
                               int* __restrict__ cursor,
                               int* __restrict__ csr_src,
                               float* __restrict__ csr_ew) {
  int i = blockIdx.x * blockDim.x + threadIdx.x;
  if (i >= ETOT) return;
  int s, d; float w;
  if (i < NEDGES) { s = ei[i]; d = ei[NEDGES + i]; w = ea[i]; }
  else            { s = d = i - NEDGES; w = 1.0f; }
  int pos = rowptr[d] + atomicAdd(&cursor[d], 1);
  csr_src[pos] = s;
  csr_ew[pos] = dinv[s] * w * dinv[d];
}

// ---------------------------------------------------------------------------
// GCN gather: wave per node; h bf16; csr_w prenormalized; unroll-4 for MLP;
// BN+ReLU fused.
// ---------------------------------------------------------------------------
__global__ __launch_bounds__(256) void gcn_gather_kernel(
    const __hip_bfloat16* __restrict__ h, const int* __restrict__ rowptr,
    const int* __restrict__ csr_src, const float* __restrict__ csr_w,
    const float* __restrict__ bias,
    const float* __restrict__ bg, const float* __restrict__ bb,
    const float* __restrict__ bm, const float* __restrict__ bv,
    float* __restrict__ out) {
  int wid = threadIdx.x >> 6, lane = threadIdx.x & 63;
  int n = blockIdx.x * 4 + wid;
  if (n >= NNODES) return;
  int e0 = rowptr[n], e1 = rowptr[n + 1];
  int c = 2 * lane;
  float ax = 0.f, ay = 0.f;
  int e = e0;
  for (; e + 4 <= e1; e += 4) {
    int s0 = csr_src[e + 0], s1 = csr_src[e + 1];
    int s2 = csr_src[e + 2], s3 = csr_src[e + 3];
    float w0 = csr_w[e + 0], w1 = csr_w[e + 1];
    float w2 = csr_w[e + 2], w3 = csr_w[e + 3];
    ushort2 u0 = *(const ushort2*)(h + (size_t)s0 * HID + c);
    ushort2 u1 = *(const ushort2*)(h + (size_t)s1 * HID + c);
    ushort2 u2 = *(const ushort2*)(h + (size_t)s2 * HID + c);
    ushort2 u3 = *(const ushort2*)(h + (size_t)s3 * HID + c);
    ax += w0 * bfu(u0.x) + w1 * bfu(u1.x) + w2 * bfu(u2.x) + w3 * bfu(u3.x);
    ay += w0 * bfu(u0.y) + w1 * bfu(u1.y) + w2 * bfu(u2.y) + w3 * bfu(u3.y);
  }
  for (; e < e1; ++e) {
    int s = csr_src[e];
    float w = csr_w[e];
    ushort2 u = *(const ushort2*)(h + (size_t)s * HID + c);
    ax += w * bfu(u.x);
    ay += w * bfu(u.y);
  }
  float ox = ax + bias[c];
  float oy = ay + bias[c + 1];
  ox = bg[c] * (ox - bm[c]) * rsqrtf(bv[c] + EPS_BN) + bb[c];
  oy = bg[c + 1] * (oy - bm[c + 1]) * rsqrtf(bv[c + 1] + EPS_BN) + bb[c + 1];
  ox = fmaxf(ox, 0.0f); oy = fmaxf(oy, 0.0f);
  float2 o; o.x = ox; o.y = oy;
  *(float2*)&out[(size_t)n * HID + c] = o;
}

// ---------------------------------------------------------------------------
extern "C" void kernel_launch(void* const* d_in, const int* in_sizes, int n_in,
                              void* d_out, int out_size, void* d_ws, size_t ws_size,
                              hipStream_t stream) {
  const float* x       = (const float*)d_in[0];
  const int*   ei      = (const int*)d_in[1];
  const float* ea      = (const float*)d_in[2];
  const float* w_gat   = (const float*)d_in[3];
  const float* att_src = (const float*)d_in[4];
  const float* att_dst = (const float*)d_in[5];
  const float* b_gat   = (const float*)d_in[6];
  const float* w2 = (const float*)d_in[7];  const float* b2 = (const float*)d_in[8];
  const float* w3 = (const float*)d_in[9];  const float* b3 = (const float*)d_in[10];
  const float* w4 = (const float*)d_in[11]; const float* b4 = (const float*)d_in[12];
  const float* bn_g = (const float*)d_in[13];
  const float* bn_b = (const float*)d_in[14];
  const float* bn_m = (const float*)d_in[15];
  const float* bn_v = (const float*)d_in[16];
  const float* w_shared = (const float*)d_in[17]; const float* b_shared = (const float*)d_in[18];
  const float* w_m1 = (const float*)d_in[19]; const float* b_m1 = (const float*)d_in[20];
  const float* w_m2 = (const float*)d_in[21]; const float* b_m2 = (const float*)d_in[22];
  const float* w_i1 = (const float*)d_in[23]; const float* b_i1 = (const float*)d_in[24];
  const float* w_i2 = (const float*)d_in[25]; const float* b_i2 = (const float*)d_in[26];
  const float* w_e1 = (const float*)d_in[27]; const float* b_e1 = (const float*)d_in[28];
  const float* w_e2 = (const float*)d_in[29]; const float* b_e2 = (const float*)d_in[30];
  float* out = (float*)d_out;

  // ---- workspace layout ----
  size_t off = 0;
  auto alloc = [&](size_t bytes) -> char* {
    char* p = (char*)d_ws + off;
    off += (bytes + 255) & ~(size_t)255;
    return p;
  };
  float* p0      = (float*)alloc((size_t)NNODES * HID * 4);
  float* p1      = (float*)alloc((size_t)NNODES * HID * 4);
  float* g       = (float*)alloc((size_t)NNODES * 64 * 4);
  __hip_bfloat16* hb = (__hip_bfloat16*)alloc((size_t)NNODES * HID * 2);
  float* a_s     = (float*)alloc((size_t)NNODES * 4 * 4);
  float* a_d     = (float*)alloc((size_t)NNODES * 4 * 4);
  float* deg     = (float*)alloc((size_t)NNODES * 4);
  float* dinv    = (float*)alloc((size_t)NNODES * 4);
  float* csr_ew  = (float*)alloc((size_t)ETOT * 4);
  int*   rowptr  = (int*)alloc((size_t)(NNODES + 1) * 4);
  int*   cnt     = (int*)alloc((size_t)NNODES * 4);
  int*   csr_src = (int*)alloc((size_t)ETOT * 4);
  int*   bsum    = (int*)alloc((size_t)NB_SCAN * 4);
  int*   boff    = (int*)alloc((size_t)NB_SCAN * 4);
  // split-bf16 transposed weights
  unsigned short* wtH = (unsigned short*)alloc(4 * 128 * 128 * 2);
  unsigned short* wtL = (unsigned short*)alloc(4 * 128 * 128 * 2);
  unsigned short* wt192h = (unsigned short*)alloc(192 * 128 * 2);
  unsigned short* wt192l = (unsigned short*)alloc(192 * 128 * 2);
  unsigned short* wtph = (unsigned short*)alloc(128 * 64 * 2);
  unsigned short* wtpl = (unsigned short*)alloc(128 * 64 * 2);
  float* b192 = (float*)alloc(192 * 4);
  float* wv_s = (float*)alloc(60 * 4);
  float* wv_d = (float*)alloc(60 * 4);

  unsigned short* wt2h = wtH + 0 * 16384; unsigned short* wt2l = wtL + 0 * 16384;
  unsigned short* wt3h = wtH + 1 * 16384; unsigned short* wt3l = wtL + 1 * 16384;
  unsigned short* wt4h = wtH + 2 * 16384; unsigned short* wt4l = wtL + 2 * 16384;
  unsigned short* wsh  = wtH + 3 * 16384; unsigned short* wsl  = wtL + 3 * 16384;

  dim3 blk256(256);
  dim3 wgrid((NNODES + 3) / 4);
  dim3 mgrid((NNODES + 63) / 64);

  // 1) CSR build: count+deg -> scan (zeroes cnt) -> dinv -> scatter(norm'd)
  hipMemsetAsync(cnt, 0, NNODES * 4, stream);
  hipMemsetAsync(deg, 0, NNODES * 4, stream);
  count_deg_kernel<<<(ETOT + 255) / 256, blk256, 0, stream>>>(ei, ea, cnt, deg);
  csr_reduce_kernel<<<NB_SCAN, blk256, 0, stream>>>(cnt, bsum);
  csr_scanb_kernel<<<1, blk256, 0, stream>>>(bsum, boff);
  csr_scan_kernel<<<NB_SCAN, blk256, 0, stream>>>(cnt, boff, rowptr);
  dinv_kernel<<<(NNODES + 255) / 256, blk256, 0, stream>>>(deg, dinv);
  scatter_kernel<<<(ETOT + 255) / 256, blk256, 0, stream>>>(
      ei, ea, dinv, rowptr, cnt, csr_src, csr_ew);

  // 2) precompute + packs (independent)
  prep_att_kernel<<<1, 64, 0, stream>>>(w_gat, att_src, att_dst, wv_s, wv_d);
  pack_wtp_kernel<<<(128 * 64 + 255) / 256, blk256, 0, stream>>>(w_gat, wtph, wtpl);
  pack_wt4_kernel<<<dim3((128 * 128 + 255) / 256, 4), blk256, 0, stream>>>(
      w2, w3, w4, w_shared, wtH, wtL);
  pack_wt192_kernel<<<(192 * 128 + 255) / 256, blk256, 0, stream>>>(
      w_m1, w_i1, w_e1, b_m1, b_i1, b_e1, wt192h, wt192l, b192);

  // 3) per-node attention logits
  a_sd_kernel<<<NB_SCAN, blk256, 0, stream>>>(x, wv_s, wv_d, a_s, a_d);

  // 4) fused GAT gather over x -> g[N,64]
  gat_fused_kernel<<<wgrid, blk256, 0, stream>>>(
      x, a_s, a_d, rowptr, csr_src, g);

  // 5) GAT post-GEMM: p0 = relu(BN0(g @ Wp + b_gat))
  gemm_mfma_kernel<2, 64><<<mgrid, blk256, 0, stream>>>(
      g, wtph, wtpl, b_gat, bn_g + 0, bn_b + 0, bn_m + 0, bn_v + 0, p0, 1, 0);

  // 6) GCN layer 2: hb(bf16) = p0 @ w2 ; gather -> p1
  gemm_mfma_kernel<2, 128><<<mgrid, blk256, 0, stream>>>(
      p0, wt2h, wt2l, nullptr, nullptr, nullptr, nullptr, nullptr, hb, 0, 1);
  gcn_gather_kernel<<<wgrid, blk256, 0, stream>>>(
      hb, rowptr, csr_src, csr_ew, b2,
      bn_g + 128, bn_b + 128, bn_m + 128, bn_v + 128, p1);

  // 7) GCN layer 3
  gemm_mfma_kernel<2, 128><<<mgrid, blk256, 0, stream>>>(
      p1, wt3h, wt3l, nullptr, nullptr, nullptr, nullptr, nullptr, hb, 0, 1);
  gcn_gather_kernel<<<wgrid, blk256, 0, stream>>>(
      hb, rowptr, csr_src, csr_ew, b3,
      bn_g + 256, bn_b + 256, bn_m + 256, bn_v + 256, p0);

  // 8) GCN layer 4
  gemm_mfma_kernel<2, 128><<<mgrid, blk256, 0, stream>>>(
      p0, wt4h, wt4l, nullptr, nullptr, nullptr, nullptr, nullptr, hb, 0, 1);
  gcn_gather_kernel<<<wgrid, blk256, 0, stream>>>(
      hb, rowptr, csr_src, csr_ew, b4,
      bn_g + 384, bn_b + 384, bn_m + 384, bn_v + 384, p1);

  // 9+10) fused shared layer + 192-GEMM + heads -> d_out
  shared_heads_kernel<<<mgrid, blk256, 0, stream>>>(
      p1, wsh, wsl, b_shared, wt192h, wt192l, b192,
      w_m2, b_m2, w_i2, b_i2, w_e2, b_e2, out);
}

// Round 18
// 319.628 us; speedup vs baseline: 1.2223x; 1.0272x over previous
//
#include <hip/hip_runtime.h>
#include <hip/hip_bf16.h>

#define NNODES 50000
#define NEDGES 400000
#define ETOT   (NEDGES + NNODES)
#define CIN    15
#define HID    128
#define HEADS  4
#define EPS_BN 1e-5f
#define NB_SCAN ((NNODES + 255) / 256)   // 196 blocks
#define NTILES  ((NNODES + 63) / 64)     // 782 row-tiles

typedef __attribute__((ext_vector_type(8))) short bf16x8_t;   // 8 bf16 = 4 VGPR
typedef __attribute__((ext_vector_type(4))) float f32x4_t;    // MFMA 16x16 acc

__device__ __forceinline__ float bfu(unsigned short u) {
  return __uint_as_float(((unsigned)u) << 16);
}
__device__ __forceinline__ unsigned short f2bf(float x) {
  union { __hip_bfloat16 b; unsigned short u; } c;
  c.b = __float2bfloat16(x);
  return c.u;
}
__device__ __forceinline__ float lrelu02(float x) {
  return x > 0.0f ? x : 0.2f * x;
}

// ---------------------------------------------------------------------------
// Persistent split-bf16 MFMA GEMM: grid-stride over 64-row tiles.
// LDS-staged A (XOR-swizzled), per-kc B loads, C via LDS stage.
// ---------------------------------------------------------------------------
template <int WPT, int KT, int NBLK>
__global__ __launch_bounds__(256) void gemm_mfma_kernel(
    const float* __restrict__ A, const unsigned short* __restrict__ WTh,
    const unsigned short* __restrict__ WTl, const float* __restrict__ bias,
    const float* __restrict__ bg, const float* __restrict__ bb,
    const float* __restrict__ bm, const float* __restrict__ bv,
    void* __restrict__ Cout, int act, int obf16) {
  constexpr int NC = WPT * 64;
  constexpr int CST = NC + 4;
  constexpr int CPR = KT / 8;
  constexpr int ABYTES = 64 * KT * 2 * 2;
  constexpr int CBYTES = 64 * CST * 4;
  constexpr int SBYTES = (ABYTES > CBYTES) ? ABYTES : CBYTES;
  __shared__ __align__(16) char smem[SBYTES];
  unsigned short* Ah = (unsigned short*)smem;
  unsigned short* Al = Ah + 64 * KT;
  float* Cs = (float*)smem;

  const int tid = threadIdx.x;
  const int wv = tid >> 6, l = tid & 63;
  const int lcol = l & 15;
  const int kg = (l >> 4) << 3;
  const int colbase = wv * (WPT * 16);

  for (int tile = blockIdx.x; tile < NTILES; tile += NBLK) {
    const int bm_ = tile * 64;
    __syncthreads();   // previous tile's Cs reads done before restaging A

    // stage A tile -> hi/lo bf16 LDS, XOR-swizzled
#pragma unroll
    for (int i = 0; i < (64 * CPR) / 256; ++i) {
      int cch = tid + 256 * i;
      int r = cch / CPR, k0 = (cch % CPR) << 3;
      int gr = bm_ + r;
      float v[8];
      if (gr < NNODES) {
        float4 v0 = *(const float4*)&A[(size_t)gr * KT + k0];
        float4 v1 = *(const float4*)&A[(size_t)gr * KT + k0 + 4];
        v[0] = v0.x; v[1] = v0.y; v[2] = v0.z; v[3] = v0.w;
        v[4] = v1.x; v[5] = v1.y; v[6] = v1.z; v[7] = v1.w;
      } else {
#pragma unroll
        for (int j = 0; j < 8; ++j) v[j] = 0.0f;
      }
      bf16x8_t hv, lv;
#pragma unroll
      for (int j = 0; j < 8; ++j) {
        unsigned short h = f2bf(v[j]);
        hv[j] = (short)h;
        lv[j] = (short)f2bf(v[j] - bfu(h));
      }
      int byte = (k0 << 1) ^ ((r & 7) << 4);
      *(bf16x8_t*)((char*)(Ah + r * KT) + byte) = hv;
      *(bf16x8_t*)((char*)(Al + r * KT) + byte) = lv;
    }
    __syncthreads();

    f32x4_t acc[4][WPT];
#pragma unroll
    for (int rt = 0; rt < 4; ++rt)
#pragma unroll
      for (int jj = 0; jj < WPT; ++jj) acc[rt][jj] = (f32x4_t){0.f, 0.f, 0.f, 0.f};

#pragma unroll
    for (int kc = 0; kc < KT / 32; ++kc) {
      bf16x8_t cbh[WPT], cbl[WPT];
#pragma unroll
      for (int jj = 0; jj < WPT; ++jj) {
        size_t boff = (size_t)(colbase + jj * 16 + lcol) * KT + kc * 32 + kg;
        cbh[jj] = *(const bf16x8_t*)(WTh + boff);
        cbl[jj] = *(const bf16x8_t*)(WTl + boff);
      }
      int k = kc * 32 + kg;
#pragma unroll
      for (int rt = 0; rt < 4; ++rt) {
        int lrow = rt * 16 + (l & 15);
        int byte = (k << 1) ^ ((lrow & 7) << 4);
        bf16x8_t ah = *(const bf16x8_t*)((const char*)(Ah + lrow * KT) + byte);
        bf16x8_t al = *(const bf16x8_t*)((const char*)(Al + lrow * KT) + byte);
#pragma unroll
        for (int jj = 0; jj < WPT; ++jj) {
          acc[rt][jj] = __builtin_amdgcn_mfma_f32_16x16x32_bf16(ah, cbh[jj], acc[rt][jj], 0, 0, 0);
          acc[rt][jj] = __builtin_amdgcn_mfma_f32_16x16x32_bf16(ah, cbl[jj], acc[rt][jj], 0, 0, 0);
          acc[rt][jj] = __builtin_amdgcn_mfma_f32_16x16x32_bf16(al, cbh[jj], acc[rt][jj], 0, 0, 0);
        }
      }
    }

    __syncthreads();   // A reads done; safe to overwrite smem with C-stage
#pragma unroll
    for (int rt = 0; rt < 4; ++rt) {
      int trow0 = rt * 16 + ((l >> 4) << 2);
#pragma unroll
      for (int jj = 0; jj < WPT; ++jj) {
        int col = colbase + jj * 16 + lcol;
        float bs = bias ? bias[col] : 0.0f;
#pragma unroll
        for (int r = 0; r < 4; ++r) {
          float vv = acc[rt][jj][r] + bs;
          if (bg) vv = bg[col] * (vv - bm[col]) * rsqrtf(bv[col] + EPS_BN) + bb[col];
          if (act) vv = fmaxf(vv, 0.0f);
          Cs[(trow0 + r) * CST + col] = vv;
        }
      }
    }
    __syncthreads();

    constexpr int NJ = (64 * NC) / 1024;
#pragma unroll
    for (int j = 0; j < NJ; ++j) {
      int f = tid * 4 + j * 1024;
      int r = f / NC, c = f - r * NC;
      int grow = bm_ + r;
      if (grow >= NNODES) continue;
      float4 v = *(const float4*)&Cs[r * CST + c];
      if (obf16) {
        ushort4 us;
        us.x = f2bf(v.x); us.y = f2bf(v.y); us.z = f2bf(v.z); us.w = f2bf(v.w);
        *(ushort4*)&((unsigned short*)Cout)[(size_t)grow * NC + c] = us;
      } else {
        *(float4*)&((float*)Cout)[(size_t)grow * NC + c] = v;
      }
    }
  }
}

// ---------------------------------------------------------------------------
// Persistent fused shared-layer + 192-GEMM + heads (grid-stride tiles).
// ---------------------------------------------------------------------------
template <int NBLK>
__global__ __launch_bounds__(256) void shared_heads_kernel(
    const float* __restrict__ A, const unsigned short* __restrict__ WSh,
    const unsigned short* __restrict__ WSl, const float* __restrict__ b_shared,
    const unsigned short* __restrict__ W2h, const unsigned short* __restrict__ W2l,
    const float* __restrict__ b192,
    const float* __restrict__ w_m2, const float* __restrict__ b_m2,
    const float* __restrict__ w_i2, const float* __restrict__ b_i2,
    const float* __restrict__ w_e2, const float* __restrict__ b_e2,
    float* __restrict__ out) {
  constexpr int KT = 128;
  constexpr int CST = 196;                 // 192 + 4
  constexpr int AC_BYTES = 64 * CST * 4;   // 50176 (C-stage aliases A-stage)
  __shared__ __align__(16) char smem[AC_BYTES + 64 * KT * 2 * 2];
  unsigned short* Ah = (unsigned short*)smem;
  unsigned short* Al = Ah + 64 * KT;
  float* Cs = (float*)smem;
  unsigned short* Hh = (unsigned short*)(smem + AC_BYTES);
  unsigned short* Hl = Hh + 64 * KT;

  const int tid = threadIdx.x;
  const int wv = tid >> 6, l = tid & 63;
  const int lcol = l & 15;
  const int kg = (l >> 4) << 3;

  for (int tile = blockIdx.x; tile < NTILES; tile += NBLK) {
    const int bm_ = tile * 64;
    __syncthreads();   // previous tile's Cs reads done

    // stage p1 tile -> split bf16 LDS (swizzled)
#pragma unroll
    for (int i = 0; i < 4; ++i) {
      int cch = tid + 256 * i;
      int r = cch >> 4, k0 = (cch & 15) << 3;
      int gr = bm_ + r;
      float v[8];
      if (gr < NNODES) {
        float4 v0 = *(const float4*)&A[(size_t)gr * KT + k0];
        float4 v1 = *(const float4*)&A[(size_t)gr * KT + k0 + 4];
        v[0] = v0.x; v[1] = v0.y; v[2] = v0.z; v[3] = v0.w;
        v[4] = v1.x; v[5] = v1.y; v[6] = v1.z; v[7] = v1.w;
      } else {
#pragma unroll
        for (int j = 0; j < 8; ++j) v[j] = 0.0f;
      }
      bf16x8_t hv, lv;
#pragma unroll
      for (int j = 0; j < 8; ++j) {
        unsigned short h = f2bf(v[j]);
        hv[j] = (short)h;
        lv[j] = (short)f2bf(v[j] - bfu(h));
      }
      int byte = (k0 << 1) ^ ((r & 7) << 4);
      *(bf16x8_t*)((char*)(Ah + r * KT) + byte) = hv;
      *(bf16x8_t*)((char*)(Al + r * KT) + byte) = lv;
    }
    __syncthreads();

    // phase B: hs = relu(p1 @ Ws + b_shared); 32 cols/wave
    {
      const int colbase = wv * 32;
      f32x4_t acc[4][2];
#pragma unroll
      for (int rt = 0; rt < 4; ++rt)
#pragma unroll
        for (int jj = 0; jj < 2; ++jj) acc[rt][jj] = (f32x4_t){0.f, 0.f, 0.f, 0.f};
#pragma unroll
      for (int kc = 0; kc < 4; ++kc) {
        bf16x8_t cbh[2], cbl[2];
#pragma unroll
        for (int jj = 0; jj < 2; ++jj) {
          size_t boff = (size_t)(colbase + jj * 16 + lcol) * KT + kc * 32 + kg;
          cbh[jj] = *(const bf16x8_t*)(WSh + boff);
          cbl[jj] = *(const bf16x8_t*)(WSl + boff);
        }
        int k = kc * 32 + kg;
#pragma unroll
        for (int rt = 0; rt < 4; ++rt) {
          int lrow = rt * 16 + (l & 15);
          int byte = (k << 1) ^ ((lrow & 7) << 4);
          bf16x8_t ah = *(const bf16x8_t*)((const char*)(Ah + lrow * KT) + byte);
          bf16x8_t al = *(const bf16x8_t*)((const char*)(Al + lrow * KT) + byte);
#pragma unroll
          for (int jj = 0; jj < 2; ++jj) {
            acc[rt][jj] = __builtin_amdgcn_mfma_f32_16x16x32_bf16(ah, cbh[jj], acc[rt][jj], 0, 0, 0);
            acc[rt][jj] = __builtin_amdgcn_mfma_f32_16x16x32_bf16(ah, cbl[jj], acc[rt][jj], 0, 0, 0);
            acc[rt][jj] = __builtin_amdgcn_mfma_f32_16x16x32_bf16(al, cbh[jj], acc[rt][jj], 0, 0, 0);
          }
        }
      }
#pragma unroll
      for (int rt = 0; rt < 4; ++rt) {
        int trow0 = rt * 16 + ((l >> 4) << 2);
#pragma unroll
        for (int jj = 0; jj < 2; ++jj) {
          int col = colbase + jj * 16 + lcol;
          float bs = b_shared[col];
#pragma unroll
          for (int r = 0; r < 4; ++r) {
            int trow = trow0 + r;
            float vv = fmaxf(acc[rt][jj][r] + bs, 0.0f);
            unsigned short hv = f2bf(vv);
            unsigned short lv = f2bf(vv - bfu(hv));
            int byte = ((trow * KT + col) << 1) ^ ((trow & 7) << 4);
            *(unsigned short*)((char*)Hh + byte) = hv;
            *(unsigned short*)((char*)Hl + byte) = lv;
          }
        }
      }
    }
    __syncthreads();

    // phase C: h192 = relu(hs @ W192 + b192); 48 cols/wave
    {
      const int colbase = wv * 48;
      f32x4_t acc[4][3];
#pragma unroll
      for (int rt = 0; rt < 4; ++rt)
#pragma unroll
        for (int jj = 0; jj < 3; ++jj) acc[rt][jj] = (f32x4_t){0.f, 0.f, 0.f, 0.f};
#pragma unroll
      for (int kc = 0; kc < 4; ++kc) {
        bf16x8_t cbh[3], cbl[3];
#pragma unroll
        for (int jj = 0; jj < 3; ++jj) {
          size_t boff = (size_t)(colbase + jj * 16 + lcol) * KT + kc * 32 + kg;
          cbh[jj] = *(const bf16x8_t*)(W2h + boff);
          cbl[jj] = *(const bf16x8_t*)(W2l + boff);
        }
        int k = kc * 32 + kg;
#pragma unroll
        for (int rt = 0; rt < 4; ++rt) {
          int lrow = rt * 16 + (l & 15);
          int byte = (k << 1) ^ ((lrow & 7) << 4);
          bf16x8_t ah = *(const bf16x8_t*)((const char*)(Hh + lrow * KT) + byte);
          bf16x8_t al = *(const bf16x8_t*)((const char*)(Hl + lrow * KT) + byte);
#pragma unroll
          for (int jj = 0; jj < 3; ++jj) {
            acc[rt][jj] = __builtin_amdgcn_mfma_f32_16x16x32_bf16(ah, cbh[jj], acc[rt][jj], 0, 0, 0);
            acc[rt][jj] = __builtin_amdgcn_mfma_f32_16x16x32_bf16(ah, cbl[jj], acc[rt][jj], 0, 0, 0);
            acc[rt][jj] = __builtin_amdgcn_mfma_f32_16x16x32_bf16(al, cbh[jj], acc[rt][jj], 0, 0, 0);
          }
        }
      }
#pragma unroll
      for (int rt = 0; rt < 4; ++rt) {
        int trow0 = rt * 16 + ((l >> 4) << 2);
#pragma unroll
        for (int jj = 0; jj < 3; ++jj) {
          int col = colbase + jj * 16 + lcol;
          float bs = b192[col];
#pragma unroll
          for (int r = 0; r < 4; ++r) {
            float vv = fmaxf(acc[rt][jj][r] + bs, 0.0f);
            Cs[(trow0 + r) * CST + col] = vv;
          }
        }
      }
    }
    __syncthreads();

    // heads: 4 threads per row; quad shfl_xor reduce
    {
      int r = tid >> 2, q = tid & 3;
      int grow = bm_ + r;
      const float* row = &Cs[r * CST];
      float p0 = 0.f, p1 = 0.f, p2 = 0.f, p3 = 0.f, p4 = 0.f;
#pragma unroll
      for (int e = 0; e < 16; ++e) {
        int c = q * 16 + e;
        float hm = row[c], hi = row[64 + c], he = row[128 + c];
        p0 += hm * w_m2[c * 2 + 0];
        p1 += hm * w_m2[c * 2 + 1];
        p2 += hi * w_i2[c * 2 + 0];
        p3 += hi * w_i2[c * 2 + 1];
        p4 += he * w_e2[c];
      }
#pragma unroll
      for (int off = 1; off < 4; off <<= 1) {
        p0 += __shfl_xor(p0, off);
        p1 += __shfl_xor(p1, off);
        p2 += __shfl_xor(p2, off);
        p3 += __shfl_xor(p3, off);
        p4 += __shfl_xor(p4, off);
      }
      if (q == 0 && grow < NNODES) {
        out[grow * 2 + 0] = p0 + b_m2[0];
        out[grow * 2 + 1] = p1 + b_m2[1];
        out[2 * NNODES + grow * 2 + 0] = p2 + b_i2[0];
        out[2 * NNODES + grow * 2 + 1] = p3 + b_i2[1];
        out[4 * NNODES + grow] = p4 + b_e2[0];
      }
    }
  }
}

// ---------------------------------------------------------------------------
// GAT precompute: wv_s[k,h] = sum_c w_gat[k, h*128+c]*att_s[h,c] (and _d)
// ---------------------------------------------------------------------------
__global__ void prep_att_kernel(const float* __restrict__ w,
                                const float* __restrict__ att_s,
                                const float* __restrict__ att_d,
                                float* __restrict__ wv_s,
                                float* __restrict__ wv_d) {
  int t = threadIdx.x;
  if (t >= 60) return;
  int k = t / 4, h = t & 3;
  float s = 0.f, d = 0.f;
  for (int c = 0; c < 128; ++c) {
    float wk = w[(size_t)k * 512 + h * 128 + c];
    s += wk * att_s[h * 128 + c];
    d += wk * att_d[h * 128 + c];
  }
  wv_s[k * 4 + h] = s;
  wv_d[k * 4 + h] = d;
}

// Pack post-GAT weight: Wp[c][j] = 0.25*w_gat[k, h*128+c], j=h*15+k (64-pad)
__global__ void pack_wtp_kernel(const float* __restrict__ w,
                                unsigned short* __restrict__ WTh,
                                unsigned short* __restrict__ WTl) {
  int i = blockIdx.x * blockDim.x + threadIdx.x;
  if (i >= 128 * 64) return;
  int c = i >> 6, j = i & 63;
  float xv = 0.f;
  if (j < 60) {
    int h = j / 15, k = j - h * 15;
    xv = 0.25f * w[(size_t)k * 512 + h * 128 + c];
  }
  unsigned short hh = f2bf(xv);
  WTh[i] = hh;
  WTl[i] = f2bf(xv - bfu(hh));
}

// ---------------------------------------------------------------------------
// Per-node attention logits: a_s[n,h] = sum_k x[n,k]*wv_s[k,h]
// ---------------------------------------------------------------------------
__global__ __launch_bounds__(256) void a_sd_kernel(
    const float* __restrict__ x, const float* __restrict__ wv_s,
    const float* __restrict__ wv_d, float* __restrict__ a_s,
    float* __restrict__ a_d) {
  __shared__ float xs[256 * 15];
  __shared__ float wvs[60], wvd[60];
  int t = threadIdx.x;
  int base = blockIdx.x * 256;
  if (t < 60) { wvs[t] = wv_s[t]; wvd[t] = wv_d[t]; }
  for (int i = t; i < 256 * 15; i += 256) {
    int gi = base * 15 + i;
    xs[i] = (gi < NNODES * 15) ? x[gi] : 0.0f;
  }
  __syncthreads();
  int n = base + t;
  if (n >= NNODES) return;
  float a0 = 0, a1 = 0, a2 = 0, a3 = 0, d0 = 0, d1 = 0, d2 = 0, d3 = 0;
#pragma unroll
  for (int k = 0; k < 15; ++k) {
    float xv = xs[t * 15 + k];
    a0 += xv * wvs[k * 4 + 0]; a1 += xv * wvs[k * 4 + 1];
    a2 += xv * wvs[k * 4 + 2]; a3 += xv * wvs[k * 4 + 3];
    d0 += xv * wvd[k * 4 + 0]; d1 += xv * wvd[k * 4 + 1];
    d2 += xv * wvd[k * 4 + 2]; d3 += xv * wvd[k * 4 + 3];
  }
  float4 A; A.x = a0; A.y = a1; A.z = a2; A.w = a3;
  float4 D; D.x = d0; D.y = d1; D.z = d2; D.w = d3;
  *(float4*)&a_s[n * 4] = A;
  *(float4*)&a_d[n * 4] = D;
}

// ---------------------------------------------------------------------------
// Fused GAT gather over x: wave per node; lane<60 -> (h=lane/15, k=lane%15).
// ---------------------------------------------------------------------------
__global__ __launch_bounds__(256) void gat_fused_kernel(
    const float* __restrict__ x, const float* __restrict__ a_s,
    const float* __restrict__ a_d, const int* __restrict__ rowptr,
    const int* __restrict__ csr_src, float* __restrict__ g) {
  int wid = threadIdx.x >> 6, lane = threadIdx.x & 63;
  int n = blockIdx.x * 4 + wid;
  if (n >= NNODES) return;
  int e0 = rowptr[n], e1 = rowptr[n + 1];
  bool on = lane < 60;
  int h = on ? (lane / 15) : 0;
  int k = on ? (lane - h * 15) : 0;
  float adn = a_d[n * 4 + h];

  float ssum = 0.f, acc = 0.f;
  int e = e0;
  for (; e + 4 <= e1; e += 4) {
    int s0 = csr_src[e + 0], s1 = csr_src[e + 1];
    int s2 = csr_src[e + 2], s3 = csr_src[e + 3];
    float as0 = a_s[s0 * 4 + h], as1 = a_s[s1 * 4 + h];
    float as2 = a_s[s2 * 4 + h], as3 = a_s[s3 * 4 + h];
    float x0 = x[(size_t)s0 * CIN + k], x1 = x[(size_t)s1 * CIN + k];
    float x2 = x[(size_t)s2 * CIN + k], x3 = x[(size_t)s3 * CIN + k];
    float ex0 = __expf(lrelu02(as0 + adn));
    float ex1 = __expf(lrelu02(as1 + adn));
    float ex2 = __expf(lrelu02(as2 + adn));
    float ex3 = __expf(lrelu02(as3 + adn));
    ssum += (ex0 + ex1) + (ex2 + ex3);
    acc += ex0 * x0 + ex1 * x1 + ex2 * x2 + ex3 * x3;
  }
  for (; e < e1; ++e) {
    int s = csr_src[e];
    float ex = __expf(lrelu02(a_s[s * 4 + h] + adn));
    ssum += ex;
    acc += ex * x[(size_t)s * CIN + k];
  }
  g[(size_t)n * 64 + lane] = on ? acc / (ssum + 1e-16f) : 0.0f;
}

// ---------------------------------------------------------------------------
// Fused pack of the four 128x128 weights -> [N][K] bf16 hi/lo (transposed)
// ---------------------------------------------------------------------------
__global__ void pack_wt4_kernel(
    const float* __restrict__ w2, const float* __restrict__ w3,
    const float* __restrict__ w4, const float* __restrict__ ws,
    unsigned short* __restrict__ Hbase, unsigned short* __restrict__ Lbase) {
  int i = blockIdx.x * blockDim.x + threadIdx.x;
  if (i >= 128 * 128) return;
  const float* W = (blockIdx.y == 0) ? w2 : (blockIdx.y == 1) ? w3
                 : (blockIdx.y == 2) ? w4 : ws;
  unsigned short* Wh = Hbase + (size_t)blockIdx.y * 128 * 128;
  unsigned short* Wl = Lbase + (size_t)blockIdx.y * 128 * 128;
  int k = i >> 7, n = i & 127;
  float x = W[i];
  unsigned short h = f2bf(x);
  Wh[n * 128 + k] = h;
  Wl[n * 128 + k] = f2bf(x - bfu(h));
}

// Pack the three 128x64 head weights into WT192 [192][128] hi/lo + b192
__global__ void pack_wt192_kernel(
    const float* __restrict__ w_m1, const float* __restrict__ w_i1,
    const float* __restrict__ w_e1, const float* __restrict__ b_m1,
    const float* __restrict__ b_i1, const float* __restrict__ b_e1,
    unsigned short* __restrict__ WTh, unsigned short* __restrict__ WTl,
    float* __restrict__ b192) {
  int i = blockIdx.x * blockDim.x + threadIdx.x;
  if (i < 192 * 128) {
    int n = i >> 7, k = i & 127;
    float x = (n < 64) ? w_m1[k * 64 + n]
            : (n < 128) ? w_i1[k * 64 + (n - 64)]
                        : w_e1[k * 64 + (n - 128)];
    unsigned short h = f2bf(x);
    WTh[(size_t)n * 128 + k] = h;
    WTl[(size_t)n * 128 + k] = f2bf(x - bfu(h));
  }
  if (i < 192) {
    b192[i] = (i < 64) ? b_m1[i] : (i < 128) ? b_i1[i - 64] : b_e1[i - 128];
  }
}

// ---------------------------------------------------------------------------
// CSR build: count+deg -> hierarchical scan -> dinv -> scatter(normalized)
// ---------------------------------------------------------------------------
__global__ void count_deg_kernel(const int* __restrict__ ei,
                                 const float* __restrict__ ea,
                                 int* __restrict__ cnt,
                                 float* __restrict__ deg) {
  int i = blockIdx.x * blockDim.x + threadIdx.x;
  if (i >= ETOT) return;
  int d; float w;
  if (i < NEDGES) { d = ei[NEDGES + i]; w = ea[i]; }
  else            { d = i - NEDGES; w = 1.0f; }
  atomicAdd(&cnt[d], 1);
  atomicAdd(&deg[d], w);
}

__global__ __launch_bounds__(256) void csr_reduce_kernel(
    const int* __restrict__ cnt, int* __restrict__ bsum) {
  __shared__ int red[256];
  int t = threadIdx.x;
  int i = blockIdx.x * 256 + t;
  red[t] = (i < NNODES) ? cnt[i] : 0;
  __syncthreads();
  for (int off = 128; off > 0; off >>= 1) {
    if (t < off) red[t] += red[t + off];
    __syncthreads();
  }
  if (t == 0) bsum[blockIdx.x] = red[0];
}

__global__ __launch_bounds__(256) void csr_scanb_kernel(
    const int* __restrict__ bsum, int* __restrict__ boff) {
  __shared__ int s[256];
  int t = threadIdx.x;
  s[t] = (t < NB_SCAN) ? bsum[t] : 0;
  __syncthreads();
  for (int off = 1; off < 256; off <<= 1) {
    int u = (t >= off) ? s[t - off] : 0;
    __syncthreads();
    s[t] += u;
    __syncthreads();
  }
  if (t < NB_SCAN) boff[t] = (t == 0) ? 0 : s[t - 1];
}

__global__ __launch_bounds__(256) void csr_scan_kernel(
    int* __restrict__ cnt, const int* __restrict__ boff,
    int* __restrict__ rowptr) {
  __shared__ int s[256];
  int t = threadIdx.x;
  int i = blockIdx.x * 256 + t;
  int v = (i < NNODES) ? cnt[i] : 0;
  s[t] = v;
  __syncthreads();
  for (int off = 1; off < 256; off <<= 1) {
    int u = (t >= off) ? s[t - off] : 0;
    __syncthreads();
    s[t] += u;
    __syncthreads();
  }
  if (i < NNODES) {
    rowptr[i] = boff[blockIdx.x] + s[t] - v;  // exclusive
    cnt[i] = 0;                               // reset -> scatter cursor
  }
  if (i == 0) rowptr[NNODES] = ETOT;
}

__global__ void dinv_kernel(const float* __restrict__ deg,
                            float* __restrict__ dinv) {
  int n = blockIdx.x * blockDim.x + threadIdx.x;
  if (n >= NNODES) return;
  float s = deg[n];
  dinv[n] = (s > 0.0f) ? rsqrtf(fmaxf(s, 1e-12f)) : 0.0f;
}

// scatter with pre-normalized GCN weight dinv[s]*w*dinv[d]
__global__ void scatter_kernel(const int* __restrict__ ei,
                               const float* __restrict__ ea,
                               const float* __restrict__ dinv,
                               const int* __restrict__ rowptr,
                               int* __restrict__ cursor,
                               int* __restrict__ csr_src,
                               float* __restrict__ csr_ew) {
  int i = blockIdx.x * blockDim.x + threadIdx.x;
  if (i >= ETOT) return;
  int s, d; float w;
  if (i < NEDGES) { s = ei[i]; d = ei[NEDGES + i]; w = ea[i]; }
  else            { s = d = i - NEDGES; w = 1.0f; }
  int pos = rowptr[d] + atomicAdd(&cursor[d], 1);
  csr_src[pos] = s;
  csr_ew[pos] = dinv[s] * w * dinv[d];
}

// ---------------------------------------------------------------------------
// GCN gather: wave per node; h bf16; csr_w prenormalized; unroll-4 for MLP;
// BN+ReLU fused.
// ---------------------------------------------------------------------------
__global__ __launch_bounds__(256) void gcn_gather_kernel(
    const __hip_bfloat16* __restrict__ h, const int* __restrict__ rowptr,
    const int* __restrict__ csr_src, const float* __restrict__ csr_w,
    const float* __restrict__ bias,
    const float* __restrict__ bg, const float* __restrict__ bb,
    const float* __restrict__ bm, const float* __restrict__ bv,
    float* __restrict__ out) {
  int wid = threadIdx.x >> 6, lane = threadIdx.x & 63;
  int n = blockIdx.x * 4 + wid;
  if (n >= NNODES) return;
  int e0 = rowptr[n], e1 = rowptr[n + 1];
  int c = 2 * lane;
  float ax = 0.f, ay = 0.f;
  int e = e0;
  for (; e + 4 <= e1; e += 4) {
    int s0 = csr_src[e + 0], s1 = csr_src[e + 1];
    int s2 = csr_src[e + 2], s3 = csr_src[e + 3];
    float w0 = csr_w[e + 0], w1 = csr_w[e + 1];
    float w2 = csr_w[e + 2], w3 = csr_w[e + 3];
    ushort2 u0 = *(const ushort2*)(h + (size_t)s0 * HID + c);
    ushort2 u1 = *(const ushort2*)(h + (size_t)s1 * HID + c);
    ushort2 u2 = *(const ushort2*)(h + (size_t)s2 * HID + c);
    ushort2 u3 = *(const ushort2*)(h + (size_t)s3 * HID + c);
    ax += w0 * bfu(u0.x) + w1 * bfu(u1.x) + w2 * bfu(u2.x) + w3 * bfu(u3.x);
    ay += w0 * bfu(u0.y) + w1 * bfu(u1.y) + w2 * bfu(u2.y) + w3 * bfu(u3.y);
  }
  for (; e < e1; ++e) {
    int s = csr_src[e];
    float w = csr_w[e];
    ushort2 u = *(const ushort2*)(h + (size_t)s * HID + c);
    ax += w * bfu(u.x);
    ay += w * bfu(u.y);
  }
  float ox = ax + bias[c];
  float oy = ay + bias[c + 1];
  ox = bg[c] * (ox - bm[c]) * rsqrtf(bv[c] + EPS_BN) + bb[c];
  oy = bg[c + 1] * (oy - bm[c + 1]) * rsqrtf(bv[c + 1] + EPS_BN) + bb[c + 1];
  ox = fmaxf(ox, 0.0f); oy = fmaxf(oy, 0.0f);
  float2 o; o.x = ox; o.y = oy;
  *(float2*)&out[(size_t)n * HID + c] = o;
}

// ---------------------------------------------------------------------------
extern "C" void kernel_launch(void* const* d_in, const int* in_sizes, int n_in,
                              void* d_out, int out_size, void* d_ws, size_t ws_size,
                              hipStream_t stream) {
  const float* x       = (const float*)d_in[0];
  const int*   ei      = (const int*)d_in[1];
  const float* ea      = (const float*)d_in[2];
  const float* w_gat   = (const float*)d_in[3];
  const float* att_src = (const float*)d_in[4];
  const float* att_dst = (const float*)d_in[5];
  const float* b_gat   = (const float*)d_in[6];
  const float* w2 = (const float*)d_in[7];  const float* b2 = (const float*)d_in[8];
  const float* w3 = (const float*)d_in[9];  const float* b3 = (const float*)d_in[10];
  const float* w4 = (const float*)d_in[11]; const float* b4 = (const float*)d_in[12];
  const float* bn_g = (const float*)d_in[13];
  const float* bn_b = (const float*)d_in[14];
  const float* bn_m = (const float*)d_in[15];
  const float* bn_v = (const float*)d_in[16];
  const float* w_shared = (const float*)d_in[17]; const float* b_shared = (const float*)d_in[18];
  const float* w_m1 = (const float*)d_in[19]; const float* b_m1 = (const float*)d_in[20];
  const float* w_m2 = (const float*)d_in[21]; const float* b_m2 = (const float*)d_in[22];
  const float* w_i1 = (const float*)d_in[23]; const float* b_i1 = (const float*)d_in[24];
  const float* w_i2 = (const float*)d_in[25]; const float* b_i2 = (const float*)d_in[26];
  const float* w_e1 = (const float*)d_in[27]; const float* b_e1 = (const float*)d_in[28];
  const float* w_e2 = (const float*)d_in[29]; const float* b_e2 = (const float*)d_in[30];
  float* out = (float*)d_out;

  // ---- workspace layout ----
  size_t off = 0;
  auto alloc = [&](size_t bytes) -> char* {
    char* p = (char*)d_ws + off;
    off += (bytes + 255) & ~(size_t)255;
    return p;
  };
  float* p0      = (float*)alloc((size_t)NNODES * HID * 4);
  float* p1      = (float*)alloc((size_t)NNODES * HID * 4);
  float* g       = (float*)alloc((size_t)NNODES * 64 * 4);
  __hip_bfloat16* hb = (__hip_bfloat16*)alloc((size_t)NNODES * HID * 2);
  float* a_s     = (float*)alloc((size_t)NNODES * 4 * 4);
  float* a_d     = (float*)alloc((size_t)NNODES * 4 * 4);
  float* deg     = (float*)alloc((size_t)NNODES * 4);
  float* dinv    = (float*)alloc((size_t)NNODES * 4);
  float* csr_ew  = (float*)alloc((size_t)ETOT * 4);
  int*   rowptr  = (int*)alloc((size_t)(NNODES + 1) * 4);
  int*   cnt     = (int*)alloc((size_t)NNODES * 4);
  int*   csr_src = (int*)alloc((size_t)ETOT * 4);
  int*   bsum    = (int*)alloc((size_t)NB_SCAN * 4);
  int*   boff    = (int*)alloc((size_t)NB_SCAN * 4);
  // split-bf16 transposed weights
  unsigned short* wtH = (unsigned short*)alloc(4 * 128 * 128 * 2);
  unsigned short* wtL = (unsigned short*)alloc(4 * 128 * 128 * 2);
  unsigned short* wt192h = (unsigned short*)alloc(192 * 128 * 2);
  unsigned short* wt192l = (unsigned short*)alloc(192 * 128 * 2);
  unsigned short* wtph = (unsigned short*)alloc(128 * 64 * 2);
  unsigned short* wtpl = (unsigned short*)alloc(128 * 64 * 2);
  float* b192 = (float*)alloc(192 * 4);
  float* wv_s = (float*)alloc(60 * 4);
  float* wv_d = (float*)alloc(60 * 4);

  unsigned short* wt2h = wtH + 0 * 16384; unsigned short* wt2l = wtL + 0 * 16384;
  unsigned short* wt3h = wtH + 1 * 16384; unsigned short* wt3l = wtL + 1 * 16384;
  unsigned short* wt4h = wtH + 2 * 16384; unsigned short* wt4l = wtL + 2 * 16384;
  unsigned short* wsh  = wtH + 3 * 16384; unsigned short* wsl  = wtL + 3 * 16384;

  dim3 blk256(256);
  dim3 wgrid((NNODES + 3) / 4);

  // 1) CSR build: count+deg -> scan (zeroes cnt) -> dinv -> scatter(norm'd)
  hipMemsetAsync(cnt, 0, NNODES * 4, stream);
  hipMemsetAsync(deg, 0, NNODES * 4, stream);
  count_deg_kernel<<<(ETOT + 255) / 256, blk256, 0, stream>>>(ei, ea, cnt, deg);
  csr_reduce_kernel<<<NB_SCAN, blk256, 0, stream>>>(cnt, bsum);
  csr_scanb_kernel<<<1, blk256, 0, stream>>>(bsum, boff);
  csr_scan_kernel<<<NB_SCAN, blk256, 0, stream>>>(cnt, boff, rowptr);
  dinv_kernel<<<(NNODES + 255) / 256, blk256, 0, stream>>>(deg, dinv);
  scatter_kernel<<<(ETOT + 255) / 256, blk256, 0, stream>>>(
      ei, ea, dinv, rowptr, cnt, csr_src, csr_ew);

  // 2) precompute + packs (independent)
  prep_att_kernel<<<1, 64, 0, stream>>>(w_gat, att_src, att_dst, wv_s, wv_d);
  pack_wtp_kernel<<<(128 * 64 + 255) / 256, blk256, 0, stream>>>(w_gat, wtph, wtpl);
  pack_wt4_kernel<<<dim3((128 * 128 + 255) / 256, 4), blk256, 0, stream>>>(
      w2, w3, w4, w_shared, wtH, wtL);
  pack_wt192_kernel<<<(192 * 128 + 255) / 256, blk256, 0, stream>>>(
      w_m1, w_i1, w_e1, b_m1, b_i1, b_e1, wt192h, wt192l, b192);

  // 3) per-node attention logits
  a_sd_kernel<<<NB_SCAN, blk256, 0, stream>>>(x, wv_s, wv_d, a_s, a_d);

  // 4) fused GAT gather over x -> g[N,64]
  gat_fused_kernel<<<wgrid, blk256, 0, stream>>>(
      x, a_s, a_d, rowptr, csr_src, g);

  // 5) GAT post-GEMM: p0 = relu(BN0(g @ Wp + b_gat))  [persistent grid 512]
  gemm_mfma_kernel<2, 64, 512><<<512, blk256, 0, stream>>>(
      g, wtph, wtpl, b_gat, bn_g + 0, bn_b + 0, bn_m + 0, bn_v + 0, p0, 1, 0);

  // 6) GCN layer 2: hb(bf16) = p0 @ w2 ; gather -> p1
  gemm_mfma_kernel<2, 128, 512><<<512, blk256, 0, stream>>>(
      p0, wt2h, wt2l, nullptr, nullptr, nullptr, nullptr, nullptr, hb, 0, 1);
  gcn_gather_kernel<<<wgrid, blk256, 0, stream>>>(
      hb, rowptr, csr_src, csr_ew, b2,
      bn_g + 128, bn_b + 128, bn_m + 128, bn_v + 128, p1);

  // 7) GCN layer 3
  gemm_mfma_kernel<2, 128, 512><<<512, blk256, 0, stream>>>(
      p1, wt3h, wt3l, nullptr, nullptr, nullptr, nullptr, nullptr, hb, 0, 1);
  gcn_gather_kernel<<<wgrid, blk256, 0, stream>>>(
      hb, rowptr, csr_src, csr_ew, b3,
      bn_g + 256, bn_b + 256, bn_m + 256, bn_v + 256, p0);

  // 8) GCN layer 4
  gemm_mfma_kernel<2, 128, 512><<<512, blk256, 0, stream>>>(
      p0, wt4h, wt4l, nullptr, nullptr, nullptr, nullptr, nullptr, hb, 0, 1);
  gcn_gather_kernel<<<wgrid, blk256, 0, stream>>>(
      hb, rowptr, csr_src, csr_ew, b4,
      bn_g + 384, bn_b + 384, bn_m + 384, bn_v + 384, p1);

  // 9+10) persistent fused shared layer + 192-GEMM + heads -> d_out
  shared_heads_kernel<256><<<256, blk256, 0, stream>>>(
      p1, wsh, wsl, b_shared, wt192h, wt192l, b192,
      w_m2, b_m2, w_i2, b_i2, w_e2, b_e2, out);
}

// Round 19
// 317.769 us; speedup vs baseline: 1.2294x; 1.0058x over previous
//
#include <hip/hip_runtime.h>
#include <hip/hip_bf16.h>

#define NNODES 50000
#define NEDGES 400000
#define ETOT   (NEDGES + NNODES)
#define CIN    15
#define HID    128
#define HEADS  4
#define EPS_BN 1e-5f
#define NB_SCAN ((NNODES + 255) / 256)   // 196 blocks
#define NTILES  ((NNODES + 63) / 64)     // 782 row-tiles

typedef __attribute__((ext_vector_type(8))) short bf16x8_t;   // 8 bf16 = 4 VGPR
typedef __attribute__((ext_vector_type(4))) float f32x4_t;    // MFMA 16x16 acc

__device__ __forceinline__ float bfu(unsigned short u) {
  return __uint_as_float(((unsigned)u) << 16);
}
__device__ __forceinline__ unsigned short f2bf(float x) {
  union { __hip_bfloat16 b; unsigned short u; } c;
  c.b = __float2bfloat16(x);
  return c.u;
}
__device__ __forceinline__ float lrelu02(float x) {
  return x > 0.0f ? x : 0.2f * x;
}

// ---------------------------------------------------------------------------
// Persistent split-bf16 MFMA GEMM: grid-stride over 64-row tiles.
// B fragments are TILE-INVARIANT -> hoisted to registers ONCE per block
// (WPT=2: 16 frags = 64 VGPR). Steady-state loop = stage A + ds_read + MFMA.
// ---------------------------------------------------------------------------
template <int WPT, int KT, int NBLK>
__global__ __launch_bounds__(256) void gemm_mfma_kernel(
    const float* __restrict__ A, const unsigned short* __restrict__ WTh,
    const unsigned short* __restrict__ WTl, const float* __restrict__ bias,
    const float* __restrict__ bg, const float* __restrict__ bb,
    const float* __restrict__ bm, const float* __restrict__ bv,
    void* __restrict__ Cout, int act, int obf16) {
  constexpr int NC = WPT * 64;
  constexpr int CST = NC + 4;
  constexpr int CPR = KT / 8;
  constexpr int NKC = KT / 32;
  constexpr int ABYTES = 64 * KT * 2 * 2;
  constexpr int CBYTES = 64 * CST * 4;
  constexpr int SBYTES = (ABYTES > CBYTES) ? ABYTES : CBYTES;
  __shared__ __align__(16) char smem[SBYTES];
  unsigned short* Ah = (unsigned short*)smem;
  unsigned short* Al = Ah + 64 * KT;
  float* Cs = (float*)smem;

  const int tid = threadIdx.x;
  const int wv = tid >> 6, l = tid & 63;
  const int lcol = l & 15;
  const int kg = (l >> 4) << 3;
  const int colbase = wv * (WPT * 16);

  // hoist ALL B fragments (tile-invariant) into registers once per block
  bf16x8_t hbh[NKC][WPT], hbl[NKC][WPT];
#pragma unroll
  for (int kc = 0; kc < NKC; ++kc)
#pragma unroll
    for (int jj = 0; jj < WPT; ++jj) {
      size_t boff = (size_t)(colbase + jj * 16 + lcol) * KT + kc * 32 + kg;
      hbh[kc][jj] = *(const bf16x8_t*)(WTh + boff);
      hbl[kc][jj] = *(const bf16x8_t*)(WTl + boff);
    }

  for (int tile = blockIdx.x; tile < NTILES; tile += NBLK) {
    const int bm_ = tile * 64;
    __syncthreads();   // previous tile's Cs reads done before restaging A

    // stage A tile -> hi/lo bf16 LDS, XOR-swizzled
#pragma unroll
    for (int i = 0; i < (64 * CPR) / 256; ++i) {
      int cch = tid + 256 * i;
      int r = cch / CPR, k0 = (cch % CPR) << 3;
      int gr = bm_ + r;
      float v[8];
      if (gr < NNODES) {
        float4 v0 = *(const float4*)&A[(size_t)gr * KT + k0];
        float4 v1 = *(const float4*)&A[(size_t)gr * KT + k0 + 4];
        v[0] = v0.x; v[1] = v0.y; v[2] = v0.z; v[3] = v0.w;
        v[4] = v1.x; v[5] = v1.y; v[6] = v1.z; v[7] = v1.w;
      } else {
#pragma unroll
        for (int j = 0; j < 8; ++j) v[j] = 0.0f;
      }
      bf16x8_t hv, lv;
#pragma unroll
      for (int j = 0; j < 8; ++j) {
        unsigned short h = f2bf(v[j]);
        hv[j] = (short)h;
        lv[j] = (short)f2bf(v[j] - bfu(h));
      }
      int byte = (k0 << 1) ^ ((r & 7) << 4);
      *(bf16x8_t*)((char*)(Ah + r * KT) + byte) = hv;
      *(bf16x8_t*)((char*)(Al + r * KT) + byte) = lv;
    }
    __syncthreads();

    f32x4_t acc[4][WPT];
#pragma unroll
    for (int rt = 0; rt < 4; ++rt)
#pragma unroll
      for (int jj = 0; jj < WPT; ++jj) acc[rt][jj] = (f32x4_t){0.f, 0.f, 0.f, 0.f};

#pragma unroll
    for (int kc = 0; kc < NKC; ++kc) {
      int k = kc * 32 + kg;
#pragma unroll
      for (int rt = 0; rt < 4; ++rt) {
        int lrow = rt * 16 + (l & 15);
        int byte = (k << 1) ^ ((lrow & 7) << 4);
        bf16x8_t ah = *(const bf16x8_t*)((const char*)(Ah + lrow * KT) + byte);
        bf16x8_t al = *(const bf16x8_t*)((const char*)(Al + lrow * KT) + byte);
#pragma unroll
        for (int jj = 0; jj < WPT; ++jj) {
          acc[rt][jj] = __builtin_amdgcn_mfma_f32_16x16x32_bf16(ah, hbh[kc][jj], acc[rt][jj], 0, 0, 0);
          acc[rt][jj] = __builtin_amdgcn_mfma_f32_16x16x32_bf16(ah, hbl[kc][jj], acc[rt][jj], 0, 0, 0);
          acc[rt][jj] = __builtin_amdgcn_mfma_f32_16x16x32_bf16(al, hbh[kc][jj], acc[rt][jj], 0, 0, 0);
        }
      }
    }

    __syncthreads();   // A reads done; safe to overwrite smem with C-stage
#pragma unroll
    for (int rt = 0; rt < 4; ++rt) {
      int trow0 = rt * 16 + ((l >> 4) << 2);
#pragma unroll
      for (int jj = 0; jj < WPT; ++jj) {
        int col = colbase + jj * 16 + lcol;
        float bs = bias ? bias[col] : 0.0f;
#pragma unroll
        for (int r = 0; r < 4; ++r) {
          float vv = acc[rt][jj][r] + bs;
          if (bg) vv = bg[col] * (vv - bm[col]) * rsqrtf(bv[col] + EPS_BN) + bb[col];
          if (act) vv = fmaxf(vv, 0.0f);
          Cs[(trow0 + r) * CST + col] = vv;
        }
      }
    }
    __syncthreads();

    constexpr int NJ = (64 * NC) / 1024;
#pragma unroll
    for (int j = 0; j < NJ; ++j) {
      int f = tid * 4 + j * 1024;
      int r = f / NC, c = f - r * NC;
      int grow = bm_ + r;
      if (grow >= NNODES) continue;
      float4 v = *(const float4*)&Cs[r * CST + c];
      if (obf16) {
        ushort4 us;
        us.x = f2bf(v.x); us.y = f2bf(v.y); us.z = f2bf(v.z); us.w = f2bf(v.w);
        *(ushort4*)&((unsigned short*)Cout)[(size_t)grow * NC + c] = us;
      } else {
        *(float4*)&((float*)Cout)[(size_t)grow * NC + c] = v;
      }
    }
  }
}

// ---------------------------------------------------------------------------
// Persistent fused shared-layer + 192-GEMM + heads (grid-stride tiles).
// Phase-B weights (16 frags) hoisted to registers; phase-C per-kc.
// ---------------------------------------------------------------------------
template <int NBLK>
__global__ __launch_bounds__(256) void shared_heads_kernel(
    const float* __restrict__ A, const unsigned short* __restrict__ WSh,
    const unsigned short* __restrict__ WSl, const float* __restrict__ b_shared,
    const unsigned short* __restrict__ W2h, const unsigned short* __restrict__ W2l,
    const float* __restrict__ b192,
    const float* __restrict__ w_m2, const float* __restrict__ b_m2,
    const float* __restrict__ w_i2, const float* __restrict__ b_i2,
    const float* __restrict__ w_e2, const float* __restrict__ b_e2,
    float* __restrict__ out) {
  constexpr int KT = 128;
  constexpr int CST = 196;                 // 192 + 4
  constexpr int AC_BYTES = 64 * CST * 4;   // 50176 (C-stage aliases A-stage)
  __shared__ __align__(16) char smem[AC_BYTES + 64 * KT * 2 * 2];
  unsigned short* Ah = (unsigned short*)smem;
  unsigned short* Al = Ah + 64 * KT;
  float* Cs = (float*)smem;
  unsigned short* Hh = (unsigned short*)(smem + AC_BYTES);
  unsigned short* Hl = Hh + 64 * KT;

  const int tid = threadIdx.x;
  const int wv = tid >> 6, l = tid & 63;
  const int lcol = l & 15;
  const int kg = (l >> 4) << 3;

  // hoist phase-B weights (tile-invariant): 4 kc x 2 jj = 16 frags
  bf16x8_t sbh[4][2], sbl[4][2];
  {
    const int colbase = wv * 32;
#pragma unroll
    for (int kc = 0; kc < 4; ++kc)
#pragma unroll
      for (int jj = 0; jj < 2; ++jj) {
        size_t boff = (size_t)(colbase + jj * 16 + lcol) * KT + kc * 32 + kg;
        sbh[kc][jj] = *(const bf16x8_t*)(WSh + boff);
        sbl[kc][jj] = *(const bf16x8_t*)(WSl + boff);
      }
  }

  for (int tile = blockIdx.x; tile < NTILES; tile += NBLK) {
    const int bm_ = tile * 64;
    __syncthreads();   // previous tile's Cs reads done

    // stage p1 tile -> split bf16 LDS (swizzled)
#pragma unroll
    for (int i = 0; i < 4; ++i) {
      int cch = tid + 256 * i;
      int r = cch >> 4, k0 = (cch & 15) << 3;
      int gr = bm_ + r;
      float v[8];
      if (gr < NNODES) {
        float4 v0 = *(const float4*)&A[(size_t)gr * KT + k0];
        float4 v1 = *(const float4*)&A[(size_t)gr * KT + k0 + 4];
        v[0] = v0.x; v[1] = v0.y; v[2] = v0.z; v[3] = v0.w;
        v[4] = v1.x; v[5] = v1.y; v[6] = v1.z; v[7] = v1.w;
      } else {
#pragma unroll
        for (int j = 0; j < 8; ++j) v[j] = 0.0f;
      }
      bf16x8_t hv, lv;
#pragma unroll
      for (int j = 0; j < 8; ++j) {
        unsigned short h = f2bf(v[j]);
        hv[j] = (short)h;
        lv[j] = (short)f2bf(v[j] - bfu(h));
      }
      int byte = (k0 << 1) ^ ((r & 7) << 4);
      *(bf16x8_t*)((char*)(Ah + r * KT) + byte) = hv;
      *(bf16x8_t*)((char*)(Al + r * KT) + byte) = lv;
    }
    __syncthreads();

    // phase B: hs = relu(p1 @ Ws + b_shared); 32 cols/wave (hoisted W)
    {
      const int colbase = wv * 32;
      f32x4_t acc[4][2];
#pragma unroll
      for (int rt = 0; rt < 4; ++rt)
#pragma unroll
        for (int jj = 0; jj < 2; ++jj) acc[rt][jj] = (f32x4_t){0.f, 0.f, 0.f, 0.f};
#pragma unroll
      for (int kc = 0; kc < 4; ++kc) {
        int k = kc * 32 + kg;
#pragma unroll
        for (int rt = 0; rt < 4; ++rt) {
          int lrow = rt * 16 + (l & 15);
          int byte = (k << 1) ^ ((lrow & 7) << 4);
          bf16x8_t ah = *(const bf16x8_t*)((const char*)(Ah + lrow * KT) + byte);
          bf16x8_t al = *(const bf16x8_t*)((const char*)(Al + lrow * KT) + byte);
#pragma unroll
          for (int jj = 0; jj < 2; ++jj) {
            acc[rt][jj] = __builtin_amdgcn_mfma_f32_16x16x32_bf16(ah, sbh[kc][jj], acc[rt][jj], 0, 0, 0);
            acc[rt][jj] = __builtin_amdgcn_mfma_f32_16x16x32_bf16(ah, sbl[kc][jj], acc[rt][jj], 0, 0, 0);
            acc[rt][jj] = __builtin_amdgcn_mfma_f32_16x16x32_bf16(al, sbh[kc][jj], acc[rt][jj], 0, 0, 0);
          }
        }
      }
#pragma unroll
      for (int rt = 0; rt < 4; ++rt) {
        int trow0 = rt * 16 + ((l >> 4) << 2);
#pragma unroll
        for (int jj = 0; jj < 2; ++jj) {
          int col = colbase + jj * 16 + lcol;
          float bs = b_shared[col];
#pragma unroll
          for (int r = 0; r < 4; ++r) {
            int trow = trow0 + r;
            float vv = fmaxf(acc[rt][jj][r] + bs, 0.0f);
            unsigned short hv = f2bf(vv);
            unsigned short lv = f2bf(vv - bfu(hv));
            int byte = ((trow * KT + col) << 1) ^ ((trow & 7) << 4);
            *(unsigned short*)((char*)Hh + byte) = hv;
            *(unsigned short*)((char*)Hl + byte) = lv;
          }
        }
      }
    }
    __syncthreads();

    // phase C: h192 = relu(hs @ W192 + b192); 48 cols/wave (per-kc W)
    {
      const int colbase = wv * 48;
      f32x4_t acc[4][3];
#pragma unroll
      for (int rt = 0; rt < 4; ++rt)
#pragma unroll
        for (int jj = 0; jj < 3; ++jj) acc[rt][jj] = (f32x4_t){0.f, 0.f, 0.f, 0.f};
#pragma unroll
      for (int kc = 0; kc < 4; ++kc) {
        bf16x8_t cbh[3], cbl[3];
#pragma unroll
        for (int jj = 0; jj < 3; ++jj) {
          size_t boff = (size_t)(colbase + jj * 16 + lcol) * KT + kc * 32 + kg;
          cbh[jj] = *(const bf16x8_t*)(W2h + boff);
          cbl[jj] = *(const bf16x8_t*)(W2l + boff);
        }
        int k = kc * 32 + kg;
#pragma unroll
        for (int rt = 0; rt < 4; ++rt) {
          int lrow = rt * 16 + (l & 15);
          int byte = (k << 1) ^ ((lrow & 7) << 4);
          bf16x8_t ah = *(const bf16x8_t*)((const char*)(Hh + lrow * KT) + byte);
          bf16x8_t al = *(const bf16x8_t*)((const char*)(Hl + lrow * KT) + byte);
#pragma unroll
          for (int jj = 0; jj < 3; ++jj) {
            acc[rt][jj] = __builtin_amdgcn_mfma_f32_16x16x32_bf16(ah, cbh[jj], acc[rt][jj], 0, 0, 0);
            acc[rt][jj] = __builtin_amdgcn_mfma_f32_16x16x32_bf16(ah, cbl[jj], acc[rt][jj], 0, 0, 0);
            acc[rt][jj] = __builtin_amdgcn_mfma_f32_16x16x32_bf16(al, cbh[jj], acc[rt][jj], 0, 0, 0);
          }
        }
      }
#pragma unroll
      for (int rt = 0; rt < 4; ++rt) {
        int trow0 = rt * 16 + ((l >> 4) << 2);
#pragma unroll
        for (int jj = 0; jj < 3; ++jj) {
          int col = colbase + jj * 16 + lcol;
          float bs = b192[col];
#pragma unroll
          for (int r = 0; r < 4; ++r) {
            float vv = fmaxf(acc[rt][jj][r] + bs, 0.0f);
            Cs[(trow0 + r) * CST + col] = vv;
          }
        }
      }
    }
    __syncthreads();

    // heads: 4 threads per row; quad shfl_xor reduce
    {
      int r = tid >> 2, q = tid & 3;
      int grow = bm_ + r;
      const float* row = &Cs[r * CST];
      float p0 = 0.f, p1 = 0.f, p2 = 0.f, p3 = 0.f, p4 = 0.f;
#pragma unroll
      for (int e = 0; e < 16; ++e) {
        int c = q * 16 + e;
        float hm = row[c], hi = row[64 + c], he = row[128 + c];
        p0 += hm * w_m2[c * 2 + 0];
        p1 += hm * w_m2[c * 2 + 1];
        p2 += hi * w_i2[c * 2 + 0];
        p3 += hi * w_i2[c * 2 + 1];
        p4 += he * w_e2[c];
      }
#pragma unroll
      for (int off = 1; off < 4; off <<= 1) {
        p0 += __shfl_xor(p0, off);
        p1 += __shfl_xor(p1, off);
        p2 += __shfl_xor(p2, off);
        p3 += __shfl_xor(p3, off);
        p4 += __shfl_xor(p4, off);
      }
      if (q == 0 && grow < NNODES) {
        out[grow * 2 + 0] = p0 + b_m2[0];
        out[grow * 2 + 1] = p1 + b_m2[1];
        out[2 * NNODES + grow * 2 + 0] = p2 + b_i2[0];
        out[2 * NNODES + grow * 2 + 1] = p3 + b_i2[1];
        out[4 * NNODES + grow] = p4 + b_e2[0];
      }
    }
  }
}

// ---------------------------------------------------------------------------
// GAT precompute: wv_s[k,h] = sum_c w_gat[k, h*128+c]*att_s[h,c] (and _d)
// ---------------------------------------------------------------------------
__global__ void prep_att_kernel(const float* __restrict__ w,
                                const float* __restrict__ att_s,
                                const float* __restrict__ att_d,
                                float* __restrict__ wv_s,
                                float* __restrict__ wv_d) {
  int t = threadIdx.x;
  if (t >= 60) return;
  int k = t / 4, h = t & 3;
  float s = 0.f, d = 0.f;
  for (int c = 0; c < 128; ++c) {
    float wk = w[(size_t)k * 512 + h * 128 + c];
    s += wk * att_s[h * 128 + c];
    d += wk * att_d[h * 128 + c];
  }
  wv_s[k * 4 + h] = s;
  wv_d[k * 4 + h] = d;
}

// Pack post-GAT weight: Wp[c][j] = 0.25*w_gat[k, h*128+c], j=h*15+k (64-pad)
__global__ void pack_wtp_kernel(const float* __restrict__ w,
                                unsigned short* __restrict__ WTh,
                                unsigned short* __restrict__ WTl) {
  int i = blockIdx.x * blockDim.x + threadIdx.x;
  if (i >= 128 * 64) return;
  int c = i >> 6, j = i & 63;
  float xv = 0.f;
  if (j < 60) {
    int h = j / 15, k = j - h * 15;
    xv = 0.25f * w[(size_t)k * 512 + h * 128 + c];
  }
  unsigned short hh = f2bf(xv);
  WTh[i] = hh;
  WTl[i] = f2bf(xv - bfu(hh));
}

// ---------------------------------------------------------------------------
// Per-node attention logits: a_s[n,h] = sum_k x[n,k]*wv_s[k,h]
// ---------------------------------------------------------------------------
__global__ __launch_bounds__(256) void a_sd_kernel(
    const float* __restrict__ x, const float* __restrict__ wv_s,
    const float* __restrict__ wv_d, float* __restrict__ a_s,
    float* __restrict__ a_d) {
  __shared__ float xs[256 * 15];
  __shared__ float wvs[60], wvd[60];
  int t = threadIdx.x;
  int base = blockIdx.x * 256;
  if (t < 60) { wvs[t] = wv_s[t]; wvd[t] = wv_d[t]; }
  for (int i = t; i < 256 * 15; i += 256) {
    int gi = base * 15 + i;
    xs[i] = (gi < NNODES * 15) ? x[gi] : 0.0f;
  }
  __syncthreads();
  int n = base + t;
  if (n >= NNODES) return;
  float a0 = 0, a1 = 0, a2 = 0, a3 = 0, d0 = 0, d1 = 0, d2 = 0, d3 = 0;
#pragma unroll
  for (int k = 0; k < 15; ++k) {
    float xv = xs[t * 15 + k];
    a0 += xv * wvs[k * 4 + 0]; a1 += xv * wvs[k * 4 + 1];
    a2 += xv * wvs[k * 4 + 2]; a3 += xv * wvs[k * 4 + 3];
    d0 += xv * wvd[k * 4 + 0]; d1 += xv * wvd[k * 4 + 1];
    d2 += xv * wvd[k * 4 + 2]; d3 += xv * wvd[k * 4 + 3];
  }
  float4 A; A.x = a0; A.y = a1; A.z = a2; A.w = a3;
  float4 D; D.x = d0; D.y = d1; D.z = d2; D.w = d3;
  *(float4*)&a_s[n * 4] = A;
  *(float4*)&a_d[n * 4] = D;
}

// ---------------------------------------------------------------------------
// Fused GAT gather over x: wave per node; lane<60 -> (h=lane/15, k=lane%15).
// ---------------------------------------------------------------------------
__global__ __launch_bounds__(256) void gat_fused_kernel(
    const float* __restrict__ x, const float* __restrict__ a_s,
    const float* __restrict__ a_d, const int* __restrict__ rowptr,
    const int* __restrict__ csr_src, float* __restrict__ g) {
  int wid = threadIdx.x >> 6, lane = threadIdx.x & 63;
  int n = blockIdx.x * 4 + wid;
  if (n >= NNODES) return;
  int e0 = rowptr[n], e1 = rowptr[n + 1];
  bool on = lane < 60;
  int h = on ? (lane / 15) : 0;
  int k = on ? (lane - h * 15) : 0;
  float adn = a_d[n * 4 + h];

  float ssum = 0.f, acc = 0.f;
  int e = e0;
  for (; e + 4 <= e1; e += 4) {
    int s0 = csr_src[e + 0], s1 = csr_src[e + 1];
    int s2 = csr_src[e + 2], s3 = csr_src[e + 3];
    float as0 = a_s[s0 * 4 + h], as1 = a_s[s1 * 4 + h];
    float as2 = a_s[s2 * 4 + h], as3 = a_s[s3 * 4 + h];
    float x0 = x[(size_t)s0 * CIN + k], x1 = x[(size_t)s1 * CIN + k];
    float x2 = x[(size_t)s2 * CIN + k], x3 = x[(size_t)s3 * CIN + k];
    float ex0 = __expf(lrelu02(as0 + adn));
    float ex1 = __expf(lrelu02(as1 + adn));
    float ex2 = __expf(lrelu02(as2 + adn));
    float ex3 = __expf(lrelu02(as3 + adn));
    ssum += (ex0 + ex1) + (ex2 + ex3);
    acc += ex0 * x0 + ex1 * x1 + ex2 * x2 + ex3 * x3;
  }
  for (; e < e1; ++e) {
    int s = csr_src[e];
    float ex = __expf(lrelu02(a_s[s * 4 + h] + adn));
    ssum += ex;
    acc += ex * x[(size_t)s * CIN + k];
  }
  g[(size_t)n * 64 + lane] = on ? acc / (ssum + 1e-16f) : 0.0f;
}

// ---------------------------------------------------------------------------
// Fused pack of the four 128x128 weights -> [N][K] bf16 hi/lo (transposed)
// ---------------------------------------------------------------------------
__global__ void pack_wt4_kernel(
    const float* __restrict__ w2, const float* __restrict__ w3,
    const float* __restrict__ w4, const float* __restrict__ ws,
    unsigned short* __restrict__ Hbase, unsigned short* __restrict__ Lbase) {
  int i = blockIdx.x * blockDim.x + threadIdx.x;
  if (i >= 128 * 128) return;
  const float* W = (blockIdx.y == 0) ? w2 : (blockIdx.y == 1) ? w3
                 : (blockIdx.y == 2) ? w4 : ws;
  unsigned short* Wh = Hbase + (size_t)blockIdx.y * 128 * 128;
  unsigned short* Wl = Lbase + (size_t)blockIdx.y * 128 * 128;
  int k = i >> 7, n = i & 127;
  float x = W[i];
  unsigned short h = f2bf(x);
  Wh[n * 128 + k] = h;
  Wl[n * 128 + k] = f2bf(x - bfu(h));
}

// Pack the three 128x64 head weights into WT192 [192][128] hi/lo + b192
__global__ void pack_wt192_kernel(
    const float* __restrict__ w_m1, const float* __restrict__ w_i1,
    const float* __restrict__ w_e1, const float* __restrict__ b_m1,
    const float* __restrict__ b_i1, const float* __restrict__ b_e1,
    unsigned short* __restrict__ WTh, unsigned short* __restrict__ WTl,
    float* __restrict__ b192) {
  int i = blockIdx.x * blockDim.x + threadIdx.x;
  if (i < 192 * 128) {
    int n = i >> 7, k = i & 127;
    float x = (n < 64) ? w_m1[k * 64 + n]
            : (n < 128) ? w_i1[k * 64 + (n - 64)]
                        : w_e1[k * 64 + (n - 128)];
    unsigned short h = f2bf(x);
    WTh[(size_t)n * 128 + k] = h;
    WTl[(size_t)n * 128 + k] = f2bf(x - bfu(h));
  }
  if (i < 192) {
    b192[i] = (i < 64) ? b_m1[i] : (i < 128) ? b_i1[i - 64] : b_e1[i - 128];
  }
}

// ---------------------------------------------------------------------------
// CSR build: count+deg -> hierarchical scan -> dinv -> scatter(normalized)
// ---------------------------------------------------------------------------
__global__ void count_deg_kernel(const int* __restrict__ ei,
                                 const float* __restrict__ ea,
                                 int* __restrict__ cnt,
                                 float* __restrict__ deg) {
  int i = blockIdx.x * blockDim.x + threadIdx.x;
  if (i >= ETOT) return;
  int d; float w;
  if (i < NEDGES) { d = ei[NEDGES + i]; w = ea[i]; }
  else            { d = i - NEDGES; w = 1.0f; }
  atomicAdd(&cnt[d], 1);
  atomicAdd(&deg[d], w);
}

__global__ __launch_bounds__(256) void csr_reduce_kernel(
    const int* __restrict__ cnt, int* __restrict__ bsum) {
  __shared__ int red[256];
  int t = threadIdx.x;
  int i = blockIdx.x * 256 + t;
  red[t] = (i < NNODES) ? cnt[i] : 0;
  __syncthreads();
  for (int off = 128; off > 0; off >>= 1) {
    if (t < off) red[t] += red[t + off];
    __syncthreads();
  }
  if (t == 0) bsum[blockIdx.x] = red[0];
}

__global__ __launch_bounds__(256) void csr_scanb_kernel(
    const int* __restrict__ bsum, int* __restrict__ boff) {
  __shared__ int s[256];
  int t = threadIdx.x;
  s[t] = (t < NB_SCAN) ? bsum[t] : 0;
  __syncthreads();
  for (int off = 1; off < 256; off <<= 1) {
    int u = (t >= off) ? s[t - off] : 0;
    __syncthreads();
    s[t] += u;
    __syncthreads();
  }
  if (t < NB_SCAN) boff[t] = (t == 0) ? 0 : s[t - 1];
}

__global__ __launch_bounds__(256) void csr_scan_kernel(
    int* __restrict__ cnt, const int* __restrict__ boff,
    int* __restrict__ rowptr) {
  __shared__ int s[256];
  int t = threadIdx.x;
  int i = blockIdx.x * 256 + t;
  int v = (i < NNODES) ? cnt[i] : 0;
  s[t] = v;
  __syncthreads();
  for (int off = 1; off < 256; off <<= 1) {
    int u = (t >= off) ? s[t - off] : 0;
    __syncthreads();
    s[t] += u;
    __syncthreads();
  }
  if (i < NNODES) {
    rowptr[i] = boff[blockIdx.x] + s[t] - v;  // exclusive
    cnt[i] = 0;                               // reset -> scatter cursor
  }
  if (i == 0) rowptr[NNODES] = ETOT;
}

__global__ void dinv_kernel(const float* __restrict__ deg,
                            float* __restrict__ dinv) {
  int n = blockIdx.x * blockDim.x + threadIdx.x;
  if (n >= NNODES) return;
  float s = deg[n];
  dinv[n] = (s > 0.0f) ? rsqrtf(fmaxf(s, 1e-12f)) : 0.0f;
}

// scatter with pre-normalized GCN weight dinv[s]*w*dinv[d]
__global__ void scatter_kernel(const int* __restrict__ ei,
                               const float* __restrict__ ea,
                               const float* __restrict__ dinv,
                               const int* __restrict__ rowptr,
                               int* __restrict__ cursor,
                               int* __restrict__ csr_src,
                               float* __restrict__ csr_ew) {
  int i = blockIdx.x * blockDim.x + threadIdx.x;
  if (i >= ETOT) return;
  int s, d; float w;
  if (i < NEDGES) { s = ei[i]; d = ei[NEDGES + i]; w = ea[i]; }
  else            { s = d = i - NEDGES; w = 1.0f; }
  int pos = rowptr[d] + atomicAdd(&cursor[d], 1);
  csr_src[pos] = s;
  csr_ew[pos] = dinv[s] * w * dinv[d];
}

// ---------------------------------------------------------------------------
// GCN gather: wave per node; h bf16; csr_w prenormalized; unroll-4 for MLP;
// BN+ReLU fused.
// ---------------------------------------------------------------------------
__global__ __launch_bounds__(256) void gcn_gather_kernel(
    const __hip_bfloat16* __restrict__ h, const int* __restrict__ rowptr,
    const int* __restrict__ csr_src, const float* __restrict__ csr_w,
    const float* __restrict__ bias,
    const float* __restrict__ bg, const float* __restrict__ bb,
    const float* __restrict__ bm, const float* __restrict__ bv,
    float* __restrict__ out) {
  int wid = threadIdx.x >> 6, lane = threadIdx.x & 63;
  int n = blockIdx.x * 4 + wid;
  if (n >= NNODES) return;
  int e0 = rowptr[n], e1 = rowptr[n + 1];
  int c = 2 * lane;
  float ax = 0.f, ay = 0.f;
  int e = e0;
  for (; e + 4 <= e1; e += 4) {
    int s0 = csr_src[e + 0], s1 = csr_src[e + 1];
    int s2 = csr_src[e + 2], s3 = csr_src[e + 3];
    float w0 = csr_w[e + 0], w1 = csr_w[e + 1];
    float w2 = csr_w[e + 2], w3 = csr_w[e + 3];
    ushort2 u0 = *(const ushort2*)(h + (size_t)s0 * HID + c);
    ushort2 u1 = *(const ushort2*)(h + (size_t)s1 * HID + c);
    ushort2 u2 = *(const ushort2*)(h + (size_t)s2 * HID + c);
    ushort2 u3 = *(const ushort2*)(h + (size_t)s3 * HID + c);
    ax += w0 * bfu(u0.x) + w1 * bfu(u1.x) + w2 * bfu(u2.x) + w3 * bfu(u3.x);
    ay += w0 * bfu(u0.y) + w1 * bfu(u1.y) + w2 * bfu(u2.y) + w3 * bfu(u3.y);
  }
  for (; e < e1; ++e) {
    int s = csr_src[e];
    float w = csr_w[e];
    ushort2 u = *(const ushort2*)(h + (size_t)s * HID + c);
    ax += w * bfu(u.x);
    ay += w * bfu(u.y);
  }
  float ox = ax + bias[c];
  float oy = ay + bias[c + 1];
  ox = bg[c] * (ox - bm[c]) * rsqrtf(bv[c] + EPS_BN) + bb[c];
  oy = bg[c + 1] * (oy - bm[c + 1]) * rsqrtf(bv[c + 1] + EPS_BN) + bb[c + 1];
  ox = fmaxf(ox, 0.0f); oy = fmaxf(oy, 0.0f);
  float2 o; o.x = ox; o.y = oy;
  *(float2*)&out[(size_t)n * HID + c] = o;
}

// ---------------------------------------------------------------------------
extern "C" void kernel_launch(void* const* d_in, const int* in_sizes, int n_in,
                              void* d_out, int out_size, void* d_ws, size_t ws_size,
                              hipStream_t stream) {
  const float* x       = (const float*)d_in[0];
  const int*   ei      = (const int*)d_in[1];
  const float* ea      = (const float*)d_in[2];
  const float* w_gat   = (const float*)d_in[3];
  const float* att_src = (const float*)d_in[4];
  const float* att_dst = (const float*)d_in[5];
  const float* b_gat   = (const float*)d_in[6];
  const float* w2 = (const float*)d_in[7];  const float* b2 = (const float*)d_in[8];
  const float* w3 = (const float*)d_in[9];  const float* b3 = (const float*)d_in[10];
  const float* w4 = (const float*)d_in[11]; const float* b4 = (const float*)d_in[12];
  const float* bn_g = (const float*)d_in[13];
  const float* bn_b = (const float*)d_in[14];
  const float* bn_m = (const float*)d_in[15];
  const float* bn_v = (const float*)d_in[16];
  const float* w_shared = (const float*)d_in[17]; const float* b_shared = (const float*)d_in[18];
  const float* w_m1 = (const float*)d_in[19]; const float* b_m1 = (const float*)d_in[20];
  const float* w_m2 = (const float*)d_in[21]; const float* b_m2 = (const float*)d_in[22];
  const float* w_i1 = (const float*)d_in[23]; const float* b_i1 = (const float*)d_in[24];
  const float* w_i2 = (const float*)d_in[25]; const float* b_i2 = (const float*)d_in[26];
  const float* w_e1 = (const float*)d_in[27]; const float* b_e1 = (const float*)d_in[28];
  const float* w_e2 = (const float*)d_in[29]; const float* b_e2 = (const float*)d_in[30];
  float* out = (float*)d_out;

  // ---- workspace layout ----
  size_t off = 0;
  auto alloc = [&](size_t bytes) -> char* {
    char* p = (char*)d_ws + off;
    off += (bytes + 255) & ~(size_t)255;
    return p;
  };
  float* p0      = (float*)alloc((size_t)NNODES * HID * 4);
  float* p1      = (float*)alloc((size_t)NNODES * HID * 4);
  float* g       = (float*)alloc((size_t)NNODES * 64 * 4);
  __hip_bfloat16* hb = (__hip_bfloat16*)alloc((size_t)NNODES * HID * 2);
  float* a_s     = (float*)alloc((size_t)NNODES * 4 * 4);
  float* a_d     = (float*)alloc((size_t)NNODES * 4 * 4);
  float* deg     = (float*)alloc((size_t)NNODES * 4);
  float* dinv    = (float*)alloc((size_t)NNODES * 4);
  float* csr_ew  = (float*)alloc((size_t)ETOT * 4);
  int*   rowptr  = (int*)alloc((size_t)(NNODES + 1) * 4);
  int*   cnt     = (int*)alloc((size_t)NNODES * 4);
  int*   csr_src = (int*)alloc((size_t)ETOT * 4);
  int*   bsum    = (int*)alloc((size_t)NB_SCAN * 4);
  int*   boff    = (int*)alloc((size_t)NB_SCAN * 4);
  // split-bf16 transposed weights
  unsigned short* wtH = (unsigned short*)alloc(4 * 128 * 128 * 2);
  unsigned short* wtL = (unsigned short*)alloc(4 * 128 * 128 * 2);
  unsigned short* wt192h = (unsigned short*)alloc(192 * 128 * 2);
  unsigned short* wt192l = (unsigned short*)alloc(192 * 128 * 2);
  unsigned short* wtph = (unsigned short*)alloc(128 * 64 * 2);
  unsigned short* wtpl = (unsigned short*)alloc(128 * 64 * 2);
  float* b192 = (float*)alloc(192 * 4);
  float* wv_s = (float*)alloc(60 * 4);
  float* wv_d = (float*)alloc(60 * 4);

  unsigned short* wt2h = wtH + 0 * 16384; unsigned short* wt2l = wtL + 0 * 16384;
  unsigned short* wt3h = wtH + 1 * 16384; unsigned short* wt3l = wtL + 1 * 16384;
  unsigned short* wt4h = wtH + 2 * 16384; unsigned short* wt4l = wtL + 2 * 16384;
  unsigned short* wsh  = wtH + 3 * 16384; unsigned short* wsl  = wtL + 3 * 16384;

  dim3 blk256(256);
  dim3 wgrid((NNODES + 3) / 4);

  // 1) CSR build: count+deg -> scan (zeroes cnt) -> dinv -> scatter(norm'd)
  hipMemsetAsync(cnt, 0, NNODES * 4, stream);
  hipMemsetAsync(deg, 0, NNODES * 4, stream);
  count_deg_kernel<<<(ETOT + 255) / 256, blk256, 0, stream>>>(ei, ea, cnt, deg);
  csr_reduce_kernel<<<NB_SCAN, blk256, 0, stream>>>(cnt, bsum);
  csr_scanb_kernel<<<1, blk256, 0, stream>>>(bsum, boff);
  csr_scan_kernel<<<NB_SCAN, blk256, 0, stream>>>(cnt, boff, rowptr);
  dinv_kernel<<<(NNODES + 255) / 256, blk256, 0, stream>>>(deg, dinv);
  scatter_kernel<<<(ETOT + 255) / 256, blk256, 0, stream>>>(
      ei, ea, dinv, rowptr, cnt, csr_src, csr_ew);

  // 2) precompute + packs (independent)
  prep_att_kernel<<<1, 64, 0, stream>>>(w_gat, att_src, att_dst, wv_s, wv_d);
  pack_wtp_kernel<<<(128 * 64 + 255) / 256, blk256, 0, stream>>>(w_gat, wtph, wtpl);
  pack_wt4_kernel<<<dim3((128 * 128 + 255) / 256, 4), blk256, 0, stream>>>(
      w2, w3, w4, w_shared, wtH, wtL);
  pack_wt192_kernel<<<(192 * 128 + 255) / 256, blk256, 0, stream>>>(
      w_m1, w_i1, w_e1, b_m1, b_i1, b_e1, wt192h, wt192l, b192);

  // 3) per-node attention logits
  a_sd_kernel<<<NB_SCAN, blk256, 0, stream>>>(x, wv_s, wv_d, a_s, a_d);

  // 4) fused GAT gather over x -> g[N,64]
  gat_fused_kernel<<<wgrid, blk256, 0, stream>>>(
      x, a_s, a_d, rowptr, csr_src, g);

  // 5) GAT post-GEMM: p0 = relu(BN0(g @ Wp + b_gat))  [persistent, B hoisted]
  gemm_mfma_kernel<2, 64, 512><<<512, blk256, 0, stream>>>(
      g, wtph, wtpl, b_gat, bn_g + 0, bn_b + 0, bn_m + 0, bn_v + 0, p0, 1, 0);

  // 6) GCN layer 2: hb(bf16) = p0 @ w2 ; gather -> p1
  gemm_mfma_kernel<2, 128, 512><<<512, blk256, 0, stream>>>(
      p0, wt2h, wt2l, nullptr, nullptr, nullptr, nullptr, nullptr, hb, 0, 1);
  gcn_gather_kernel<<<wgrid, blk256, 0, stream>>>(
      hb, rowptr, csr_src, csr_ew, b2,
      bn_g + 128, bn_b + 128, bn_m + 128, bn_v + 128, p1);

  // 7) GCN layer 3
  gemm_mfma_kernel<2, 128, 512><<<512, blk256, 0, stream>>>(
      p1, wt3h, wt3l, nullptr, nullptr, nullptr, nullptr, nullptr, hb, 0, 1);
  gcn_gather_kernel<<<wgrid, blk256, 0, stream>>>(
      hb, rowptr, csr_src, csr_ew, b3,
      bn_g + 256, bn_b + 256, bn_m + 256, bn_v + 256, p0);

  // 8) GCN layer 4
  gemm_mfma_kernel<2, 128, 512><<<512, blk256, 0, stream>>>(
      p0, wt4h, wt4l, nullptr, nullptr, nullptr, nullptr, nullptr, hb, 0, 1);
  gcn_gather_kernel<<<wgrid, blk256, 0, stream>>>(
      hb, rowptr, csr_src, csr_ew, b4,
      bn_g + 384, bn_b + 384, bn_m + 384, bn_v + 384, p1);

  // 9+10) persistent fused shared layer + 192-GEMM + heads -> d_out
  shared_heads_kernel<196><<<196, blk256, 0, stream>>>(
      p1, wsh, wsl, b_shared, wt192h, wt192l, b192,
      w_m2, b_m2, w_i2, b_i2, w_e2, b_e2, out);
}